// Round 2
// baseline (630.711 us; speedup 1.0000x reference)
//
#include <hip/hip_runtime.h>
#include <hip/hip_bf16.h>

#define EMB 1024
#define NH 16
#define HD 64
#define BATCH 8
#define SEQ 1024
#define ROWS (BATCH*SEQ)   // 8192

typedef unsigned short ushort_t;
typedef __attribute__((ext_vector_type(8))) short bf16x8;
typedef __attribute__((ext_vector_type(4))) float f32x4;

__device__ __forceinline__ float bf2f(ushort_t u){
    union { unsigned int i; float f; } v; v.i = ((unsigned int)u) << 16; return v.f;
}
__device__ __forceinline__ ushort_t f2bf(float f){
    unsigned int u = __float_as_uint(f);
    unsigned int r = (u + 0x7FFFu + ((u >> 16) & 1u)) >> 16;
    return (ushort_t)r;
}
__device__ __forceinline__ void gload16(const ushort_t* g, ushort_t* l){
    __builtin_amdgcn_global_load_lds(
        (const __attribute__((address_space(1))) void*)g,
        (__attribute__((address_space(3))) void*)l,
        16, 0, 0);
}
__device__ __forceinline__ void fence_barrier(){
    asm volatile("" ::: "memory");
    __builtin_amdgcn_s_barrier();
    asm volatile("" ::: "memory");
}
__device__ __forceinline__ void drain_barrier(){
    asm volatile("s_waitcnt vmcnt(0)" ::: "memory");
    __builtin_amdgcn_s_barrier();
    asm volatile("" ::: "memory");
}
// exact-erf GELU via A&S 7.1.26 (|err| < 1.5e-7)
__device__ __forceinline__ float gelu_f(float v){
    float x = fabsf(v) * 0.70710678118654752f;
    float t = __builtin_amdgcn_rcpf(1.0f + 0.3275911f * x);
    float poly = t*(0.254829592f + t*(-0.284496736f + t*(1.421413741f + t*(-1.453152027f + t*1.061405429f))));
    float erfa = 1.0f - poly * __expf(-x*x);
    float erfv = (v >= 0.f) ? erfa : -erfa;
    return 0.5f * v * (1.0f + erfv);
}

// ---------------- fused prep: LN1 (blocks 0..8191) + all 6 weight transposes ----------------
__global__ __launch_bounds__(256) void prep_kernel(const float* __restrict__ x,
                                                   const float* __restrict__ ln1_g,
                                                   const float* __restrict__ ln1_b,
                                                   ushort_t* __restrict__ h1,
                                                   const float* __restrict__ wq,
                                                   const float* __restrict__ wk,
                                                   const float* __restrict__ wv,
                                                   const float* __restrict__ w_proj,
                                                   const float* __restrict__ w1,
                                                   const float* __restrict__ w2,
                                                   ushort_t* __restrict__ wqkv_t,
                                                   ushort_t* __restrict__ wproj_t,
                                                   ushort_t* __restrict__ w1_t,
                                                   ushort_t* __restrict__ w2_t){
    int bid = blockIdx.x;
    int tid = threadIdx.x;
    if (bid < ROWS){
        __shared__ float ss[4], qq[4];
        __shared__ float mu_s, sc_s;
        const float* xr = x + (size_t)bid * EMB;
        float4 f = *(const float4*)(xr + tid*4);
        float v[4] = {f.x, f.y, f.z, f.w};
        float s = v[0]+v[1]+v[2]+v[3];
        float q = v[0]*v[0]+v[1]*v[1]+v[2]*v[2]+v[3]*v[3];
        #pragma unroll
        for (int o = 32; o > 0; o >>= 1){ s += __shfl_down(s, o); q += __shfl_down(q, o); }
        int wave = tid >> 6, lane = tid & 63;
        if (lane == 0){ ss[wave] = s; qq[wave] = q; }
        __syncthreads();
        if (tid == 0){
            float S = ss[0]+ss[1]+ss[2]+ss[3];
            float Q = qq[0]+qq[1]+qq[2]+qq[3];
            float mu = S * (1.0f/EMB);
            float var = Q * (1.0f/EMB) - mu*mu;
            mu_s = mu; sc_s = rsqrtf(var + 1e-5f);
        }
        __syncthreads();
        float mu = mu_s, sc = sc_s;
        float4 gu = *(const float4*)(ln1_g + tid*4);
        float4 bu = *(const float4*)(ln1_b + tid*4);
        ushort4 o4;
        o4.x = f2bf((v[0]-mu)*sc*gu.x + bu.x);
        o4.y = f2bf((v[1]-mu)*sc*gu.y + bu.y);
        o4.z = f2bf((v[2]-mu)*sc*gu.z + bu.z);
        o4.w = f2bf((v[3]-mu)*sc*gu.w + bu.w);
        *(ushort4*)(h1 + (size_t)bid*EMB + tid*4) = o4;
    } else {
        __shared__ ushort_t t[32][33];
        int j = bid - ROWS;
        const float* in; ushort_t* out; int K, N, bx, by;
        if (j < 3072){
            int which = j >> 10, jj = j & 1023;
            in = (which == 0) ? wq : (which == 1) ? wk : wv;
            out = wqkv_t + (size_t)which * 1024 * 1024;
            K = 1024; N = 1024; bx = jj & 31; by = jj >> 5;
        } else if (j < 4096){
            int jj = j - 3072;
            in = w_proj; out = wproj_t; K = 1024; N = 1024; bx = jj & 31; by = jj >> 5;
        } else if (j < 8192){
            int jj = j - 4096;
            in = w1; out = w1_t; K = 1024; N = 4096; bx = jj & 127; by = jj >> 7;
        } else {
            int jj = j - 8192;
            in = w2; out = w2_t; K = 4096; N = 1024; bx = jj & 31; by = jj >> 5;
        }
        int tx = tid & 31, ty = tid >> 5;
        #pragma unroll
        for (int r = 0; r < 4; ++r)
            t[ty + r*8][tx] = f2bf(in[(size_t)(by*32 + ty + r*8) * N + bx*32 + tx]);
        __syncthreads();
        #pragma unroll
        for (int r = 0; r < 4; ++r)
            out[(size_t)(bx*32 + ty + r*8) * K + by*32 + tx] = t[tx][ty + r*8];
    }
}

// ---------------- LayerNorm (row = 1024), f32 in -> bf16 out ----------------
__global__ __launch_bounds__(256) void ln_kernel(const float* __restrict__ xin,
                                                 const float* __restrict__ g,
                                                 const float* __restrict__ bia,
                                                 ushort_t* __restrict__ out){
    int row = blockIdx.x;
    int tid = threadIdx.x;
    const float* x = xin + (size_t)row * EMB;
    float4 f = *(const float4*)(x + tid*4);
    float v[4] = {f.x, f.y, f.z, f.w};
    float s = v[0]+v[1]+v[2]+v[3];
    float q = v[0]*v[0]+v[1]*v[1]+v[2]*v[2]+v[3]*v[3];
    #pragma unroll
    for (int o = 32; o > 0; o >>= 1){ s += __shfl_down(s, o); q += __shfl_down(q, o); }
    __shared__ float ss[4], qq[4];
    __shared__ float mu_s, sc_s;
    int wave = tid >> 6, lane = tid & 63;
    if (lane == 0){ ss[wave] = s; qq[wave] = q; }
    __syncthreads();
    if (tid == 0){
        float S = ss[0]+ss[1]+ss[2]+ss[3];
        float Q = qq[0]+qq[1]+qq[2]+qq[3];
        float mu = S * (1.0f/EMB);
        float var = Q * (1.0f/EMB) - mu*mu;
        mu_s = mu; sc_s = rsqrtf(var + 1e-5f);
    }
    __syncthreads();
    float mu = mu_s, sc = sc_s;
    float4 gu = *(const float4*)(g + tid*4);
    float4 bu = *(const float4*)(bia + tid*4);
    ushort4 o4;
    o4.x = f2bf((v[0]-mu)*sc*gu.x + bu.x);
    o4.y = f2bf((v[1]-mu)*sc*gu.y + bu.y);
    o4.z = f2bf((v[2]-mu)*sc*gu.z + bu.z);
    o4.w = f2bf((v[3]-mu)*sc*gu.w + bu.w);
    *(ushort4*)(out + (size_t)row*EMB + tid*4) = o4;
}

// ---------------- GEMM: 256 x (NBL*64) tile, 8 waves, fragment-major LDS, 4-phase pipeline ----
// LDS holds MFMA fragments in lane-linear order: chunk (frag*64 + lane) is a 16B b128 read at
// base + lane*16 -> zero bank conflicts by construction. global_load_lds dest is lane-linear;
// the per-lane GLOBAL source does the permutation: wave w round i stages fragment i*8+w
// (fm = i*4 + (w>>1), fk = w&1), chunk id (fm*2+fk)*64+l == i*512 + w*64 + l (bijective).
// Pipeline: all of tile t+1's loads issue at the TOP of tile t (buf^1 is free once tile t
// starts) -> full-tile prefetch lead; boundary = vmcnt(0)+barrier (lead >> latency).
// 4 phases x 16 (or 8) MFMA with raw s_barrier separators + setprio around MFMA clusters.
// 16x16x32 MFMA: a-frag lane l = A[m: l&15][k: (l>>4)*8..+8]; C/D col=lane&15, row=(l>>4)*4+reg.
// MODE 0: plain -> bf16 | 1: +bias+resid -> f32 | 2: +bias+GELU -> bf16 | 3: +bias+resid -> f32
template<int MODE, int NBL>   // NBL = per-wave n-blocks: 4 -> BN=256, 2 -> BN=128
__global__ __launch_bounds__(512, 2) void gemm8_kernel(const ushort_t* __restrict__ A,
                                                       const ushort_t* __restrict__ Bt,
                                                       const float* __restrict__ bias,
                                                       const float* __restrict__ resid,
                                                       void* __restrict__ out,
                                                       int M, int N, int K){
    constexpr int BN = NBL * 64;
    __shared__ ushort_t As[2][16384];        // 2 x 32 KB  (256 rows x 64 k)
    __shared__ ushort_t Bs[2][NBL*4096];     // 2 x 16/32 KB

    int tid = threadIdx.x;
    int lane = tid & 63, w = tid >> 6;       // 8 waves
    int l15 = lane & 15, lq = lane >> 4;
    int wm = w >> 2, wn = w & 3;             // 2 x 4 wave grid; per-wave out 128 x NBL*16
    int bid = blockIdx.x;
    int m0 = (bid & 31) * 256, n0 = (bid >> 5) * BN;

    f32x4 acc[8][NBL];
    #pragma unroll
    for (int i=0;i<8;i++)
        #pragma unroll
        for (int j=0;j<NBL;j++) acc[i][j] = (f32x4){0.f,0.f,0.f,0.f};

    // staging source pointers: wave w, round i stages fragment i*8+w
    const ushort_t* pA = A  + (size_t)(m0 + (w>>1)*16 + l15)*K + (w&1)*32 + lq*8;
    const ushort_t* pB = Bt + (size_t)(n0 + (w>>1)*16 + l15)*K + (w&1)*32 + lq*8;

    auto stage = [&](int buf, int k0){
        #pragma unroll
        for (int i = 0; i < 4; ++i)
            gload16(pA + (size_t)i*64*K + k0, &As[buf][i*4096 + w*512]);
        #pragma unroll
        for (int i = 0; i < NBL; ++i)
            gload16(pB + (size_t)i*64*K + k0, &Bs[buf][i*4096 + w*512]);
    };

    stage(0, 0);
    drain_barrier();

    int NT = K >> 6;
    for (int t = 0; t < NT; ++t){
        int cur = t & 1;
        const ushort_t* Ab = As[cur];
        const ushort_t* Bb = Bs[cur];
        if (t + 1 < NT) stage(cur ^ 1, (t + 1) << 6);   // full-tile prefetch lead

        // b-frags for the whole tile (register-cached)
        bf16x8 bfr[NBL][2];
        #pragma unroll
        for (int nb=0;nb<NBL;nb++)
            #pragma unroll
            for (int fk=0;fk<2;fk++)
                bfr[nb][fk] = *(const bf16x8*)&Bb[(((wn*NBL + nb)*2 + fk)*64 + lane)*8];

        #pragma unroll
        for (int p = 0; p < 4; ++p){
            bf16x8 af[2][2];
            #pragma unroll
            for (int q=0;q<2;q++)
                #pragma unroll
                for (int fk=0;fk<2;fk++)
                    af[q][fk] = *(const bf16x8*)&Ab[(((wm*8 + 2*p + q)*2 + fk)*64 + lane)*8];
            __builtin_amdgcn_s_setprio(1);
            #pragma unroll
            for (int q=0;q<2;q++)
                #pragma unroll
                for (int nb=0;nb<NBL;nb++){
                    acc[2*p+q][nb] = __builtin_amdgcn_mfma_f32_16x16x32_bf16(af[q][0], bfr[nb][0], acc[2*p+q][nb], 0,0,0);
                    acc[2*p+q][nb] = __builtin_amdgcn_mfma_f32_16x16x32_bf16(af[q][1], bfr[nb][1], acc[2*p+q][nb], 0,0,0);
                }
            __builtin_amdgcn_s_setprio(0);
            if (p < 3) fence_barrier();                 // phase separator, no drain
        }
        drain_barrier();                                 // tile boundary: prefetch landed + WAR
    }

    // epilogue: C/D col = n_base + nb*16 + l15, row = m_base + mb*16 + lq*4 + r
    int n_base = n0 + wn*(NBL*16);
    int m_base = m0 + wm*128 + lq*4;
    float bn[NBL];
    #pragma unroll
    for (int nb=0;nb<NBL;nb++) bn[nb] = (MODE != 0) ? bias[n_base + nb*16 + l15] : 0.f;
    #pragma unroll
    for (int mb=0;mb<8;mb++){
        #pragma unroll
        for (int nb=0;nb<NBL;nb++){
            int n = n_base + nb*16 + l15;
            #pragma unroll
            for (int r=0;r<4;r++){
                int m = m_base + mb*16 + r;
                float v = acc[mb][nb][r];
                size_t idx = (size_t)m*N + n;
                if (MODE == 0){
                    ((ushort_t*)out)[idx] = f2bf(v);
                } else if (MODE == 1 || MODE == 3){
                    ((float*)out)[idx] = v + bn[nb] + resid[idx];
                } else {
                    ((ushort_t*)out)[idx] = f2bf(gelu_f(v + bn[nb]));
                }
            }
        }
    }
}

// ---------------- Flash attention (causal), S^T formulation ----------------
__global__ __launch_bounds__(256) void attn_kernel(const ushort_t* __restrict__ qkv,
                                                   ushort_t* __restrict__ attn_out){
    __shared__ ushort_t Qs[128*64];    // [q][d], gload chunk-swizzled
    __shared__ ushort_t Ks[64*64];     // [kv][d], gload chunk-swizzled
    __shared__ ushort_t Vts[64][72];   // V^T [d][kv], write-swizzled
    __shared__ ushort_t Ps[128*64];    // P [q][kv], XOR-slotted

    int tid = threadIdx.x;
    int lane = tid & 63, wave = tid >> 6;
    int quad = lane >> 4, l15 = lane & 15;
    int pair = blockIdx.x;         // 0..3
    int bh = blockIdx.y;           // 0..127
    int b = bh >> 4, h = bh & 15;
    size_t tb = (size_t)b * SEQ;

    int lr = lane >> 3, lch = lane & 7;   // gload lane decomposition
    int tr = tid >> 3;                    // V staging: rows 0..31
    int tc = (tid & 7) * 8;
    int sw_w = tid & 7;
    int sx = l15 & 7;                     // fragment-read chunk swizzle

    for (int t = 0; t < 2; ++t){
        int qi = t ? (7 - pair) : pair;

        {
            const ushort_t* gq = qkv + (size_t)(tb + qi*128 + wave*32 + lr)*3072 + h*64 + (lch^lr)*8;
            ushort_t* lq = &Qs[(wave*32)*64];
            #pragma unroll
            for (int p = 0; p < 4; ++p)
                gload16(gq + (size_t)(p*8)*3072, lq + p*8*64);
        }

        f32x4 o_acc[4][2];
        #pragma unroll
        for (int i=0;i<4;i++)
            #pragma unroll
            for (int j=0;j<2;j++) o_acc[i][j] = (f32x4){0.f,0.f,0.f,0.f};
        float m_st[2] = {-1e30f, -1e30f};
        float l_st[2] = {0.f, 0.f};

        int nj = 2*qi + 2;
        for (int j = 0; j < nj; ++j){
            {
                const ushort_t* gk = qkv + (size_t)(tb + j*64 + wave*16 + lr)*3072 + 1024 + h*64 + (lch^lr)*8;
                ushort_t* lk = &Ks[(wave*16)*64];
                gload16(gk, lk);
                gload16(gk + (size_t)8*3072, lk + 8*64);
            }
            #pragma unroll
            for (int p = 0; p < 2; ++p){
                int r = tr + p*32;
                bf16x8 vv = *(const bf16x8*)(qkv + (size_t)(tb + j*64 + r)*3072 + 2048 + h*64 + tc);
                int kcol = r ^ (sw_w << 3);
                #pragma unroll
                for (int c = 0; c < 8; ++c) Vts[tc + c][kcol] = (ushort_t)vv[c];
            }
            __syncthreads();

            // S^T[kv 64][q 32/wave] = K·Q^T
            f32x4 st[4][2];
            #pragma unroll
            for (int mt=0;mt<4;mt++)
                #pragma unroll
                for (int nt=0;nt<2;nt++) st[mt][nt] = (f32x4){0.f,0.f,0.f,0.f};
            #pragma unroll
            for (int kf = 0; kf < 2; ++kf){
                int ch = (kf*4 + quad) ^ sx;
                bf16x8 ak[4], bq[2];
                #pragma unroll
                for (int mt=0;mt<4;mt++) ak[mt] = *(const bf16x8*)&Ks[(mt*16 + l15)*64 + ch*8];
                #pragma unroll
                for (int nt=0;nt<2;nt++) bq[nt] = *(const bf16x8*)&Qs[(wave*32 + nt*16 + l15)*64 + ch*8];
                #pragma unroll
                for (int mt=0;mt<4;mt++)
                    #pragma unroll
                    for (int nt=0;nt<2;nt++)
                        st[mt][nt] = __builtin_amdgcn_mfma_f32_16x16x32_bf16(ak[mt], bq[nt], st[mt][nt], 0,0,0);
            }

            bool need_mask = (j >= 2*qi);
            #pragma unroll
            for (int mt=0;mt<4;mt++)
                #pragma unroll
                for (int nt=0;nt<2;nt++)
                    #pragma unroll
                    for (int r=0;r<4;r++){
                        float s = st[mt][nt][r] * 0.125f;
                        if (need_mask){
                            int kg = j*64 + mt*16 + quad*4 + r;
                            int qg = qi*128 + wave*32 + nt*16 + l15;
                            if (kg > qg) s = -1e30f;
                        }
                        st[mt][nt][r] = s;
                    }

            #pragma unroll
            for (int nt = 0; nt < 2; ++nt){
                float mx = st[0][nt][0];
                #pragma unroll
                for (int mt=0;mt<4;mt++)
                    #pragma unroll
                    for (int r=0;r<4;r++) mx = fmaxf(mx, st[mt][nt][r]);
                mx = fmaxf(mx, __shfl_xor(mx, 16));
                mx = fmaxf(mx, __shfl_xor(mx, 32));
                float mnew = fmaxf(m_st[nt], mx);
                float al = __expf(m_st[nt] - mnew);
                float ps = 0.f;
                #pragma unroll
                for (int mt=0;mt<4;mt++)
                    #pragma unroll
                    for (int r=0;r<4;r++){
                        float p = __expf(st[mt][nt][r] - mnew);
                        st[mt][nt][r] = p;
                        ps += p;
                    }
                ps += __shfl_xor(ps, 16);
                ps += __shfl_xor(ps, 32);
                l_st[nt] = l_st[nt]*al + ps;
                m_st[nt] = mnew;
                #pragma unroll
                for (int mtd=0;mtd<4;mtd++)
                    #pragma unroll
                    for (int r=0;r<4;r++) o_acc[mtd][nt][r] *= al;
                #pragma unroll
                for (int mt=0;mt<4;mt++){
                    int slot = (mt*2 + (quad>>1)) ^ sx;
                    ushort4 pk;
                    pk.x = f2bf(st[mt][nt][0]); pk.y = f2bf(st[mt][nt][1]);
                    pk.z = f2bf(st[mt][nt][2]); pk.w = f2bf(st[mt][nt][3]);
                    *(ushort4*)&Ps[(wave*32 + nt*16 + l15)*64 + slot*8 + (quad&1)*4] = pk;
                }
            }

            // O^T[d 64][q 32/wave] += V^T·P^T
            #pragma unroll
            for (int kf = 0; kf < 2; ++kf){
                bf16x8 av[4], bp[2];
                #pragma unroll
                for (int mtd=0;mtd<4;mtd++){
                    int d = mtd*16 + l15;
                    int col = (kf*32 + quad*8) ^ (((d >> 3) & 7) << 3);
                    av[mtd] = *(const bf16x8*)&Vts[d][col];
                }
                #pragma unroll
                for (int nt=0;nt<2;nt++){
                    int ch = (kf*4 + quad) ^ sx;
                    bp[nt] = *(const bf16x8*)&Ps[(wave*32 + nt*16 + l15)*64 + ch*8];
                }
                #pragma unroll
                for (int mtd=0;mtd<4;mtd++)
                    #pragma unroll
                    for (int nt=0;nt<2;nt++)
                        o_acc[mtd][nt] = __builtin_amdgcn_mfma_f32_16x16x32_bf16(av[mtd], bp[nt], o_acc[mtd][nt], 0,0,0);
            }
            __syncthreads();
        }

        #pragma unroll
        for (int nt = 0; nt < 2; ++nt){
            float inv = 1.0f / l_st[nt];
            size_t tok = tb + qi*128 + wave*32 + nt*16 + l15;
            #pragma unroll
            for (int mtd = 0; mtd < 4; ++mtd){
                ushort4 ok;
                ok.x = f2bf(o_acc[mtd][nt][0]*inv); ok.y = f2bf(o_acc[mtd][nt][1]*inv);
                ok.z = f2bf(o_acc[mtd][nt][2]*inv); ok.w = f2bf(o_acc[mtd][nt][3]*inv);
                *(ushort4*)(attn_out + tok*EMB + h*64 + mtd*16 + quad*4) = ok;
            }
        }
    }
}

extern "C" void kernel_launch(void* const* d_in, const int* in_sizes, int n_in,
                              void* d_out, int out_size, void* d_ws, size_t ws_size,
                              hipStream_t stream){
    const float* x      = (const float*)d_in[0];
    const float* ln1_g  = (const float*)d_in[1];
    const float* ln1_b  = (const float*)d_in[2];
    const float* wq     = (const float*)d_in[3];
    const float* wk     = (const float*)d_in[4];
    const float* wv     = (const float*)d_in[5];
    const float* w_proj = (const float*)d_in[6];
    const float* b_proj = (const float*)d_in[7];
    const float* ln2_g  = (const float*)d_in[8];
    const float* ln2_b  = (const float*)d_in[9];
    const float* w1     = (const float*)d_in[10];
    const float* b1     = (const float*)d_in[11];
    const float* w2     = (const float*)d_in[12];
    const float* b2     = (const float*)d_in[13];
    float* outp = (float*)d_out;

    char* ws = (char*)d_ws;
    size_t off = 0;
    auto alloc = [&](size_t bytes)->char*{ char* p = ws + off; off += (bytes + 255) & ~255ULL; return p; };
    ushort_t* wqkv_t = (ushort_t*)alloc((size_t)3072*1024*2);
    ushort_t* wproj_t= (ushort_t*)alloc((size_t)1024*1024*2);
    ushort_t* w1_t   = (ushort_t*)alloc((size_t)4096*1024*2);
    ushort_t* w2_t   = (ushort_t*)alloc((size_t)1024*4096*2);
    ushort_t* qkv    = (ushort_t*)alloc((size_t)ROWS*3072*2);
    ushort_t* hbuf   = (ushort_t*)alloc((size_t)ROWS*1024*2);
    float*    out32  = (float*)  alloc((size_t)ROWS*1024*4);
    ushort_t* mid    = (ushort_t*)alloc((size_t)ROWS*4096*2);
    ushort_t* h1 = hbuf;
    ushort_t* attn = hbuf;   // h1 dead after qkv GEMM
    ushort_t* h2 = qkv;      // qkv dead after attention

    dim3 blk(256);
    dim3 gblk(512);
    // blocks: 8192 LN1 rows + 3072 (wq/wk/wv) + 1024 (wproj) + 4096 (w1) + 4096 (w2)
    prep_kernel<<<dim3(20480), blk, 0, stream>>>(x, ln1_g, ln1_b, h1,
                                                 wq, wk, wv, w_proj, w1, w2,
                                                 wqkv_t, wproj_t, w1_t, w2_t);
    // grids (all exact multiples of 256 blocks): 768 / 256 / 512 / 256
    gemm8_kernel<0,2><<<dim3(32*(3072/128)), gblk, 0, stream>>>(h1, wqkv_t, nullptr, nullptr, qkv, ROWS, 3072, 1024);
    attn_kernel<<<dim3(4,128), blk, 0, stream>>>(qkv, attn);
    gemm8_kernel<1,2><<<dim3(32*(1024/128)), gblk, 0, stream>>>(attn, wproj_t, b_proj, x, out32, ROWS, 1024, 1024);
    ln_kernel<<<ROWS, blk, 0, stream>>>(out32, ln2_g, ln2_b, h2);
    gemm8_kernel<2,4><<<dim3(32*(4096/256)), gblk, 0, stream>>>(h2, w1_t, b1, nullptr, mid, ROWS, 4096, 1024);
    gemm8_kernel<3,2><<<dim3(32*(1024/128)), gblk, 0, stream>>>(mid, w2_t, b2, out32, outp, ROWS, 1024, 4096);
}

// Round 3
// 607.385 us; speedup vs baseline: 1.0384x; 1.0384x over previous
//
#include <hip/hip_runtime.h>
#include <hip/hip_bf16.h>

#define EMB 1024
#define NH 16
#define HD 64
#define BATCH 8
#define SEQ 1024
#define ROWS (BATCH*SEQ)   // 8192

typedef unsigned short ushort_t;
typedef __attribute__((ext_vector_type(8))) short bf16x8;
typedef __attribute__((ext_vector_type(4))) float f32x4;

__device__ __forceinline__ float bf2f(ushort_t u){
    union { unsigned int i; float f; } v; v.i = ((unsigned int)u) << 16; return v.f;
}
__device__ __forceinline__ ushort_t f2bf(float f){
    unsigned int u = __float_as_uint(f);
    unsigned int r = (u + 0x7FFFu + ((u >> 16) & 1u)) >> 16;
    return (ushort_t)r;
}
__device__ __forceinline__ void gload16(const ushort_t* g, ushort_t* l){
    __builtin_amdgcn_global_load_lds(
        (const __attribute__((address_space(1))) void*)g,
        (__attribute__((address_space(3))) void*)l,
        16, 0, 0);
}
// exact-erf GELU via A&S 7.1.26 (|err| < 1.5e-7)
__device__ __forceinline__ float gelu_f(float v){
    float x = fabsf(v) * 0.70710678118654752f;
    float t = __builtin_amdgcn_rcpf(1.0f + 0.3275911f * x);
    float poly = t*(0.254829592f + t*(-0.284496736f + t*(1.421413741f + t*(-1.453152027f + t*1.061405429f))));
    float erfa = 1.0f - poly * __expf(-x*x);
    float erfv = (v >= 0.f) ? erfa : -erfa;
    return 0.5f * v * (1.0f + erfv);
}

// ---------------- fused prep: LN1 (blocks 0..8191) + all 6 weight transposes ----------------
__global__ __launch_bounds__(256) void prep_kernel(const float* __restrict__ x,
                                                   const float* __restrict__ ln1_g,
                                                   const float* __restrict__ ln1_b,
                                                   ushort_t* __restrict__ h1,
                                                   const float* __restrict__ wq,
                                                   const float* __restrict__ wk,
                                                   const float* __restrict__ wv,
                                                   const float* __restrict__ w_proj,
                                                   const float* __restrict__ w1,
                                                   const float* __restrict__ w2,
                                                   ushort_t* __restrict__ wqkv_t,
                                                   ushort_t* __restrict__ wproj_t,
                                                   ushort_t* __restrict__ w1_t,
                                                   ushort_t* __restrict__ w2_t){
    int bid = blockIdx.x;
    int tid = threadIdx.x;
    if (bid < ROWS){
        __shared__ float ss[4], qq[4];
        __shared__ float mu_s, sc_s;
        const float* xr = x + (size_t)bid * EMB;
        float4 f = *(const float4*)(xr + tid*4);
        float v[4] = {f.x, f.y, f.z, f.w};
        float s = v[0]+v[1]+v[2]+v[3];
        float q = v[0]*v[0]+v[1]*v[1]+v[2]*v[2]+v[3]*v[3];
        #pragma unroll
        for (int o = 32; o > 0; o >>= 1){ s += __shfl_down(s, o); q += __shfl_down(q, o); }
        int wave = tid >> 6, lane = tid & 63;
        if (lane == 0){ ss[wave] = s; qq[wave] = q; }
        __syncthreads();
        if (tid == 0){
            float S = ss[0]+ss[1]+ss[2]+ss[3];
            float Q = qq[0]+qq[1]+qq[2]+qq[3];
            float mu = S * (1.0f/EMB);
            float var = Q * (1.0f/EMB) - mu*mu;
            mu_s = mu; sc_s = rsqrtf(var + 1e-5f);
        }
        __syncthreads();
        float mu = mu_s, sc = sc_s;
        float4 gu = *(const float4*)(ln1_g + tid*4);
        float4 bu = *(const float4*)(ln1_b + tid*4);
        ushort4 o4;
        o4.x = f2bf((v[0]-mu)*sc*gu.x + bu.x);
        o4.y = f2bf((v[1]-mu)*sc*gu.y + bu.y);
        o4.z = f2bf((v[2]-mu)*sc*gu.z + bu.z);
        o4.w = f2bf((v[3]-mu)*sc*gu.w + bu.w);
        *(ushort4*)(h1 + (size_t)bid*EMB + tid*4) = o4;
    } else {
        __shared__ ushort_t t[32][33];
        int j = bid - ROWS;
        const float* in; ushort_t* out; int K, N, bx, by;
        if (j < 3072){
            int which = j >> 10, jj = j & 1023;
            in = (which == 0) ? wq : (which == 1) ? wk : wv;
            out = wqkv_t + (size_t)which * 1024 * 1024;
            K = 1024; N = 1024; bx = jj & 31; by = jj >> 5;
        } else if (j < 4096){
            int jj = j - 3072;
            in = w_proj; out = wproj_t; K = 1024; N = 1024; bx = jj & 31; by = jj >> 5;
        } else if (j < 8192){
            int jj = j - 4096;
            in = w1; out = w1_t; K = 1024; N = 4096; bx = jj & 127; by = jj >> 7;
        } else {
            int jj = j - 8192;
            in = w2; out = w2_t; K = 4096; N = 1024; bx = jj & 31; by = jj >> 5;
        }
        int tx = tid & 31, ty = tid >> 5;
        #pragma unroll
        for (int r = 0; r < 4; ++r)
            t[ty + r*8][tx] = f2bf(in[(size_t)(by*32 + ty + r*8) * N + bx*32 + tx]);
        __syncthreads();
        #pragma unroll
        for (int r = 0; r < 4; ++r)
            out[(size_t)(bx*32 + ty + r*8) * K + by*32 + tx] = t[tx][ty + r*8];
    }
}

// ---------------- LayerNorm (row = 1024), f32 in -> bf16 out ----------------
__global__ __launch_bounds__(256) void ln_kernel(const float* __restrict__ xin,
                                                 const float* __restrict__ g,
                                                 const float* __restrict__ bia,
                                                 ushort_t* __restrict__ out){
    int row = blockIdx.x;
    int tid = threadIdx.x;
    const float* x = xin + (size_t)row * EMB;
    float4 f = *(const float4*)(x + tid*4);
    float v[4] = {f.x, f.y, f.z, f.w};
    float s = v[0]+v[1]+v[2]+v[3];
    float q = v[0]*v[0]+v[1]*v[1]+v[2]*v[2]+v[3]*v[3];
    #pragma unroll
    for (int o = 32; o > 0; o >>= 1){ s += __shfl_down(s, o); q += __shfl_down(q, o); }
    __shared__ float ss[4], qq[4];
    __shared__ float mu_s, sc_s;
    int wave = tid >> 6, lane = tid & 63;
    if (lane == 0){ ss[wave] = s; qq[wave] = q; }
    __syncthreads();
    if (tid == 0){
        float S = ss[0]+ss[1]+ss[2]+ss[3];
        float Q = qq[0]+qq[1]+qq[2]+qq[3];
        float mu = S * (1.0f/EMB);
        float var = Q * (1.0f/EMB) - mu*mu;
        mu_s = mu; sc_s = rsqrtf(var + 1e-5f);
    }
    __syncthreads();
    float mu = mu_s, sc = sc_s;
    float4 gu = *(const float4*)(g + tid*4);
    float4 bu = *(const float4*)(bia + tid*4);
    ushort4 o4;
    o4.x = f2bf((v[0]-mu)*sc*gu.x + bu.x);
    o4.y = f2bf((v[1]-mu)*sc*gu.y + bu.y);
    o4.z = f2bf((v[2]-mu)*sc*gu.z + bu.z);
    o4.w = f2bf((v[3]-mu)*sc*gu.w + bu.w);
    *(ushort4*)(out + (size_t)row*EMB + tid*4) = o4;
}

// ---------------- GEMM: (NBM*32) x 256 tile, 8 waves, fragment-major LDS, ----------------
// ---------------- 4-phase counted-vmcnt pipeline (T3+T4+T5) ----------------
// Fragment-major LDS: frag f occupies chunks [f*512 .. f*512+511] ushorts; lane reads 16B at
// f*1024B + lane*16 -> zero bank conflicts (proven round 2). gload_lds dest is lane-linear;
// per-lane GLOBAL source does the permutation.
// Stage rounds regrouped so round r = exactly the frags consumed at phase r of the NEXT tile:
//   A round r, wave w -> fm=(w>>2)*NBM + 2r|r + ((w>>1)&1), fk=w&1 (see fragA0+4r below)
//   B round r, wave w -> frag r*8+w (n_frag = r*4+(w>>1), needed only by waves wn=r, at ph0)
// Steady-state per-phase waits (8 loads/tile, order B0..B3,A0..A3):
//   ph0 vmcnt(4), ph1 vmcnt(5), ph2 vmcnt(6), ph3 vmcnt(3); last tile: 2,1,0,-.
// NBM=4 (6 loads, order A0,B0,B1,B2,B3,A1): ph1 vmcnt(4), ph3 vmcnt(1); last: ph1 vmcnt(0).
// Never vmcnt(0) in steady state -> loads span phases (T4). setprio around MFMA (T5).
// MODE 0: plain -> bf16 | 1: +bias+resid -> f32 | 2: +bias+GELU -> bf16 | 3: +bias+resid -> f32
template<int MODE, int NBM>   // NBM: m-frags per wave; BM = NBM*32 (8 -> 256, 4 -> 128)
__global__ __launch_bounds__(512, 2) void gemm8_kernel(const ushort_t* __restrict__ A,
                                                       const ushort_t* __restrict__ Bt,
                                                       const float* __restrict__ bias,
                                                       const float* __restrict__ resid,
                                                       void* __restrict__ out,
                                                       int M, int N, int K){
    constexpr int BM  = NBM * 32;
    constexpr int MPP = NBM / 4;          // m-frags per phase per wave (2 or 1)
    constexpr int MT_ = 8192 / BM;        // m-tiles (32 or 64), power of 2
    __shared__ ushort_t As[2][NBM*4*512]; // NBM=8: 2x32KB, NBM=4: 2x16KB
    __shared__ ushort_t Bs[2][16384];     // 2x32KB (BN=256)

    int tid = threadIdx.x;
    int lane = tid & 63, w = tid >> 6;    // 8 waves
    int l15 = lane & 15, lq = lane >> 4;
    int wm = w >> 2, wn = w & 3;          // 2M x 4N wave grid; per-wave out (NBM*16) x 64... x4 nb
    int bid = blockIdx.x;
    int m0 = (bid & (MT_-1)) * BM, n0 = (bid / MT_) * 256;

    f32x4 acc[NBM][4];
    #pragma unroll
    for (int i=0;i<NBM;i++)
        #pragma unroll
        for (int j=0;j<4;j++) acc[i][j] = (f32x4){0.f,0.f,0.f,0.f};

    // staging bases: A round r -> frag fragA0+4r from row base + 32r; B round r -> frag r*8+w from row base + 64r
    const ushort_t* baseA = A  + (size_t)(m0 + ((w>>2)*NBM + ((w>>1)&1))*16 + l15)*K + (w&1)*32 + lq*8;
    const ushort_t* baseB = Bt + (size_t)(n0 + (w>>1)*16 + l15)*K + (w&1)*32 + lq*8;
    int fragA0 = ((w>>2)*NBM + ((w>>1)&1))*2 + (w&1);

    auto stageA = [&](int buf, int k0, int r){
        gload16(baseA + (size_t)(32*r)*K + k0, &As[buf][(fragA0 + 4*r)*512]);
    };
    auto stageB = [&](int buf, int k0, int r){
        gload16(baseB + (size_t)(64*r)*K + k0, &Bs[buf][(r*8 + w)*512]);
    };

    // ---- prologue: stage buf0 in canonical order, counted wait, barrier ----
    if constexpr (NBM == 8){
        stageB(0,0,0); stageB(0,0,1); stageB(0,0,2); stageB(0,0,3);
        stageA(0,0,0); stageA(0,0,1); stageA(0,0,2); stageA(0,0,3);
        asm volatile("s_waitcnt vmcnt(3)" ::: "memory");
    } else {
        stageA(0,0,0); stageB(0,0,0); stageB(0,0,1); stageB(0,0,2); stageB(0,0,3); stageA(0,0,1);
        asm volatile("s_waitcnt vmcnt(1)" ::: "memory");
    }
    __builtin_amdgcn_s_barrier();
    asm volatile("" ::: "memory");

#define PHASE(p, STAGE_AND_WAIT)                                                          \
    {                                                                                     \
        bf16x8 af[MPP][2];                                                                \
        _Pragma("unroll")                                                                 \
        for (int q=0;q<MPP;q++){                                                          \
            int fm = wm*NBM + (p)*MPP + q;                                                \
            _Pragma("unroll")                                                             \
            for (int fk=0;fk<2;fk++)                                                      \
                af[q][fk] = *(const bf16x8*)&Ab[(fm*2+fk)*512 + lane*8];                  \
        }                                                                                 \
        STAGE_AND_WAIT;                                                                   \
        asm volatile("" ::: "memory");                                                    \
        __builtin_amdgcn_s_barrier();                                                     \
        asm volatile("s_waitcnt lgkmcnt(0)" ::: "memory");                                \
        __builtin_amdgcn_sched_barrier(0);                                                \
        __builtin_amdgcn_s_setprio(1);                                                    \
        _Pragma("unroll")                                                                 \
        for (int q=0;q<MPP;q++)                                                           \
            _Pragma("unroll")                                                             \
            for (int nb=0;nb<4;nb++){                                                     \
                acc[(p)*MPP+q][nb] = __builtin_amdgcn_mfma_f32_16x16x32_bf16(af[q][0], bfr[nb][0], acc[(p)*MPP+q][nb], 0,0,0); \
                acc[(p)*MPP+q][nb] = __builtin_amdgcn_mfma_f32_16x16x32_bf16(af[q][1], bfr[nb][1], acc[(p)*MPP+q][nb], 0,0,0); \
            }                                                                             \
        __builtin_amdgcn_s_setprio(0);                                                    \
        asm volatile("" ::: "memory");                                                    \
        __builtin_amdgcn_s_barrier();                                                     \
        asm volatile("" ::: "memory");                                                    \
    }

    int NT = K >> 6;
    for (int t = 0; t < NT; ++t){
        const int cur = t & 1, nxt = cur ^ 1;
        const int nk0 = (t+1) << 6;
        const bool last = (t == NT-1);
        const ushort_t* Ab = As[cur];
        const ushort_t* Bb = Bs[cur];

        // B-frags for whole tile (register-cached; guaranteed by prev ph3 wait+barrier)
        bf16x8 bfr[4][2];
        #pragma unroll
        for (int nb=0;nb<4;nb++)
            #pragma unroll
            for (int fk=0;fk<2;fk++)
                bfr[nb][fk] = *(const bf16x8*)&Bb[((wn*4+nb)*2+fk)*512 + lane*8];

        if constexpr (NBM == 8){
            PHASE(0,
                if (!last){ stageB(nxt,nk0,0); stageB(nxt,nk0,1);
                            asm volatile("s_waitcnt vmcnt(4)" ::: "memory"); }
                else      { asm volatile("s_waitcnt vmcnt(2)" ::: "memory"); } )
            PHASE(1,
                if (!last){ stageB(nxt,nk0,2); stageB(nxt,nk0,3);
                            asm volatile("s_waitcnt vmcnt(5)" ::: "memory"); }
                else      { asm volatile("s_waitcnt vmcnt(1)" ::: "memory"); } )
            PHASE(2,
                if (!last){ stageA(nxt,nk0,0); stageA(nxt,nk0,1);
                            asm volatile("s_waitcnt vmcnt(6)" ::: "memory"); }
                else      { asm volatile("s_waitcnt vmcnt(0)" ::: "memory"); } )
            PHASE(3,
                if (!last){ stageA(nxt,nk0,2); stageA(nxt,nk0,3);
                            asm volatile("s_waitcnt vmcnt(3)" ::: "memory"); } )
        } else {
            PHASE(0,
                if (!last){ stageA(nxt,nk0,0); stageB(nxt,nk0,0); } )
            PHASE(1,
                if (!last){ stageB(nxt,nk0,1); stageB(nxt,nk0,2);
                            asm volatile("s_waitcnt vmcnt(4)" ::: "memory"); }
                else      { asm volatile("s_waitcnt vmcnt(0)" ::: "memory"); } )
            PHASE(2,
                if (!last){ stageB(nxt,nk0,3); stageA(nxt,nk0,1); } )
            PHASE(3,
                if (!last){ asm volatile("s_waitcnt vmcnt(1)" ::: "memory"); } )
        }
    }
#undef PHASE

    // epilogue: C/D col = n_base + nb*16 + l15, row = m_base + mb*16 + lq*4 + r
    int n_base = n0 + wn*64;
    int m_base = m0 + wm*(NBM*16) + lq*4;
    float bn[4];
    #pragma unroll
    for (int nb=0;nb<4;nb++) bn[nb] = (MODE != 0) ? bias[n_base + nb*16 + l15] : 0.f;
    #pragma unroll
    for (int mb=0;mb<NBM;mb++){
        #pragma unroll
        for (int nb=0;nb<4;nb++){
            int n = n_base + nb*16 + l15;
            #pragma unroll
            for (int r=0;r<4;r++){
                int m = m_base + mb*16 + r;
                float v = acc[mb][nb][r];
                size_t idx = (size_t)m*N + n;
                if (MODE == 0){
                    ((ushort_t*)out)[idx] = f2bf(v);
                } else if (MODE == 1 || MODE == 3){
                    ((float*)out)[idx] = v + bn[nb] + resid[idx];
                } else {
                    ((ushort_t*)out)[idx] = f2bf(gelu_f(v + bn[nb]));
                }
            }
        }
    }
}

// ---------------- Flash attention (causal), S^T formulation ----------------
__global__ __launch_bounds__(256) void attn_kernel(const ushort_t* __restrict__ qkv,
                                                   ushort_t* __restrict__ attn_out){
    __shared__ ushort_t Qs[128*64];    // [q][d], gload chunk-swizzled
    __shared__ ushort_t Ks[64*64];     // [kv][d], gload chunk-swizzled
    __shared__ ushort_t Vts[64][72];   // V^T [d][kv], write-swizzled
    __shared__ ushort_t Ps[128*64];    // P [q][kv], XOR-slotted

    int tid = threadIdx.x;
    int lane = tid & 63, wave = tid >> 6;
    int quad = lane >> 4, l15 = lane & 15;
    int pair = blockIdx.x;         // 0..3
    int bh = blockIdx.y;           // 0..127
    int b = bh >> 4, h = bh & 15;
    size_t tb = (size_t)b * SEQ;

    int lr = lane >> 3, lch = lane & 7;   // gload lane decomposition
    int tr = tid >> 3;                    // V staging: rows 0..31
    int tc = (tid & 7) * 8;
    int sw_w = tid & 7;
    int sx = l15 & 7;                     // fragment-read chunk swizzle

    for (int t = 0; t < 2; ++t){
        int qi = t ? (7 - pair) : pair;

        {
            const ushort_t* gq = qkv + (size_t)(tb + qi*128 + wave*32 + lr)*3072 + h*64 + (lch^lr)*8;
            ushort_t* lq = &Qs[(wave*32)*64];
            #pragma unroll
            for (int p = 0; p < 4; ++p)
                gload16(gq + (size_t)(p*8)*3072, lq + p*8*64);
        }

        f32x4 o_acc[4][2];
        #pragma unroll
        for (int i=0;i<4;i++)
            #pragma unroll
            for (int j=0;j<2;j++) o_acc[i][j] = (f32x4){0.f,0.f,0.f,0.f};
        float m_st[2] = {-1e30f, -1e30f};
        float l_st[2] = {0.f, 0.f};

        int nj = 2*qi + 2;
        for (int j = 0; j < nj; ++j){
            {
                const ushort_t* gk = qkv + (size_t)(tb + j*64 + wave*16 + lr)*3072 + 1024 + h*64 + (lch^lr)*8;
                ushort_t* lk = &Ks[(wave*16)*64];
                gload16(gk, lk);
                gload16(gk + (size_t)8*3072, lk + 8*64);
            }
            #pragma unroll
            for (int p = 0; p < 2; ++p){
                int r = tr + p*32;
                bf16x8 vv = *(const bf16x8*)(qkv + (size_t)(tb + j*64 + r)*3072 + 2048 + h*64 + tc);
                int kcol = r ^ (sw_w << 3);
                #pragma unroll
                for (int c = 0; c < 8; ++c) Vts[tc + c][kcol] = (ushort_t)vv[c];
            }
            __syncthreads();

            // S^T[kv 64][q 32/wave] = K·Q^T
            f32x4 st[4][2];
            #pragma unroll
            for (int mt=0;mt<4;mt++)
                #pragma unroll
                for (int nt=0;nt<2;nt++) st[mt][nt] = (f32x4){0.f,0.f,0.f,0.f};
            #pragma unroll
            for (int kf = 0; kf < 2; ++kf){
                int ch = (kf*4 + quad) ^ sx;
                bf16x8 ak[4], bq[2];
                #pragma unroll
                for (int mt=0;mt<4;mt++) ak[mt] = *(const bf16x8*)&Ks[(mt*16 + l15)*64 + ch*8];
                #pragma unroll
                for (int nt=0;nt<2;nt++) bq[nt] = *(const bf16x8*)&Qs[(wave*32 + nt*16 + l15)*64 + ch*8];
                #pragma unroll
                for (int mt=0;mt<4;mt++)
                    #pragma unroll
                    for (int nt=0;nt<2;nt++)
                        st[mt][nt] = __builtin_amdgcn_mfma_f32_16x16x32_bf16(ak[mt], bq[nt], st[mt][nt], 0,0,0);
            }

            bool need_mask = (j >= 2*qi);
            #pragma unroll
            for (int mt=0;mt<4;mt++)
                #pragma unroll
                for (int nt=0;nt<2;nt++)
                    #pragma unroll
                    for (int r=0;r<4;r++){
                        float s = st[mt][nt][r] * 0.125f;
                        if (need_mask){
                            int kg = j*64 + mt*16 + quad*4 + r;
                            int qg = qi*128 + wave*32 + nt*16 + l15;
                            if (kg > qg) s = -1e30f;
                        }
                        st[mt][nt][r] = s;
                    }

            #pragma unroll
            for (int nt = 0; nt < 2; ++nt){
                float mx = st[0][nt][0];
                #pragma unroll
                for (int mt=0;mt<4;mt++)
                    #pragma unroll
                    for (int r=0;r<4;r++) mx = fmaxf(mx, st[mt][nt][r]);
                mx = fmaxf(mx, __shfl_xor(mx, 16));
                mx = fmaxf(mx, __shfl_xor(mx, 32));
                float mnew = fmaxf(m_st[nt], mx);
                float al = __expf(m_st[nt] - mnew);
                float ps = 0.f;
                #pragma unroll
                for (int mt=0;mt<4;mt++)
                    #pragma unroll
                    for (int r=0;r<4;r++){
                        float p = __expf(st[mt][nt][r] - mnew);
                        st[mt][nt][r] = p;
                        ps += p;
                    }
                ps += __shfl_xor(ps, 16);
                ps += __shfl_xor(ps, 32);
                l_st[nt] = l_st[nt]*al + ps;
                m_st[nt] = mnew;
                #pragma unroll
                for (int mtd=0;mtd<4;mtd++)
                    #pragma unroll
                    for (int r=0;r<4;r++) o_acc[mtd][nt][r] *= al;
                #pragma unroll
                for (int mt=0;mt<4;mt++){
                    int slot = (mt*2 + (quad>>1)) ^ sx;
                    ushort4 pk;
                    pk.x = f2bf(st[mt][nt][0]); pk.y = f2bf(st[mt][nt][1]);
                    pk.z = f2bf(st[mt][nt][2]); pk.w = f2bf(st[mt][nt][3]);
                    *(ushort4*)&Ps[(wave*32 + nt*16 + l15)*64 + slot*8 + (quad&1)*4] = pk;
                }
            }

            // O^T[d 64][q 32/wave] += V^T·P^T
            #pragma unroll
            for (int kf = 0; kf < 2; ++kf){
                bf16x8 av[4], bp[2];
                #pragma unroll
                for (int mtd=0;mtd<4;mtd++){
                    int d = mtd*16 + l15;
                    int col = (kf*32 + quad*8) ^ (((d >> 3) & 7) << 3);
                    av[mtd] = *(const bf16x8*)&Vts[d][col];
                }
                #pragma unroll
                for (int nt=0;nt<2;nt++){
                    int ch = (kf*4 + quad) ^ sx;
                    bp[nt] = *(const bf16x8*)&Ps[(wave*32 + nt*16 + l15)*64 + ch*8];
                }
                #pragma unroll
                for (int mtd=0;mtd<4;mtd++)
                    #pragma unroll
                    for (int nt=0;nt<2;nt++)
                        o_acc[mtd][nt] = __builtin_amdgcn_mfma_f32_16x16x32_bf16(av[mtd], bp[nt], o_acc[mtd][nt], 0,0,0);
            }
            __syncthreads();
        }

        #pragma unroll
        for (int nt = 0; nt < 2; ++nt){
            float inv = 1.0f / l_st[nt];
            size_t tok = tb + qi*128 + wave*32 + nt*16 + l15;
            #pragma unroll
            for (int mtd = 0; mtd < 4; ++mtd){
                ushort4 ok;
                ok.x = f2bf(o_acc[mtd][nt][0]*inv); ok.y = f2bf(o_acc[mtd][nt][1]*inv);
                ok.z = f2bf(o_acc[mtd][nt][2]*inv); ok.w = f2bf(o_acc[mtd][nt][3]*inv);
                *(ushort4*)(attn_out + tok*EMB + h*64 + mtd*16 + quad*4) = ok;
            }
        }
    }
}

extern "C" void kernel_launch(void* const* d_in, const int* in_sizes, int n_in,
                              void* d_out, int out_size, void* d_ws, size_t ws_size,
                              hipStream_t stream){
    const float* x      = (const float*)d_in[0];
    const float* ln1_g  = (const float*)d_in[1];
    const float* ln1_b  = (const float*)d_in[2];
    const float* wq     = (const float*)d_in[3];
    const float* wk     = (const float*)d_in[4];
    const float* wv     = (const float*)d_in[5];
    const float* w_proj = (const float*)d_in[6];
    const float* b_proj = (const float*)d_in[7];
    const float* ln2_g  = (const float*)d_in[8];
    const float* ln2_b  = (const float*)d_in[9];
    const float* w1     = (const float*)d_in[10];
    const float* b1     = (const float*)d_in[11];
    const float* w2     = (const float*)d_in[12];
    const float* b2     = (const float*)d_in[13];
    float* outp = (float*)d_out;

    char* ws = (char*)d_ws;
    size_t off = 0;
    auto alloc = [&](size_t bytes)->char*{ char* p = ws + off; off += (bytes + 255) & ~255ULL; return p; };
    ushort_t* wqkv_t = (ushort_t*)alloc((size_t)3072*1024*2);
    ushort_t* wproj_t= (ushort_t*)alloc((size_t)1024*1024*2);
    ushort_t* w1_t   = (ushort_t*)alloc((size_t)4096*1024*2);
    ushort_t* w2_t   = (ushort_t*)alloc((size_t)1024*4096*2);
    ushort_t* qkv    = (ushort_t*)alloc((size_t)ROWS*3072*2);
    ushort_t* hbuf   = (ushort_t*)alloc((size_t)ROWS*1024*2);
    float*    out32  = (float*)  alloc((size_t)ROWS*1024*4);
    ushort_t* mid    = (ushort_t*)alloc((size_t)ROWS*4096*2);
    ushort_t* h1 = hbuf;
    ushort_t* attn = hbuf;   // h1 dead after qkv GEMM
    ushort_t* h2 = qkv;      // qkv dead after attention

    dim3 blk(256);
    dim3 gblk(512);
    // blocks: 8192 LN1 rows + 3072 (wq/wk/wv) + 1024 (wproj) + 4096 (w1) + 4096 (w2)
    prep_kernel<<<dim3(20480), blk, 0, stream>>>(x, ln1_g, ln1_b, h1,
                                                 wq, wk, wv, w_proj, w1, w2,
                                                 wqkv_t, wproj_t, w1_t, w2_t);
    // grids (all exact multiples of 256 blocks at 1 block/CU):
    // QKV: BM=128 -> 64 x 12 = 768 | proj: 64 x 4 = 256 | MLP1: BM=256 -> 32 x 16 = 512 | MLP2: 64 x 4 = 256
    gemm8_kernel<0,4><<<dim3(64*(3072/256)), gblk, 0, stream>>>(h1, wqkv_t, nullptr, nullptr, qkv, ROWS, 3072, 1024);
    attn_kernel<<<dim3(4,128), blk, 0, stream>>>(qkv, attn);
    gemm8_kernel<1,4><<<dim3(64*(1024/256)), gblk, 0, stream>>>(attn, wproj_t, b_proj, x, out32, ROWS, 1024, 1024);
    ln_kernel<<<ROWS, blk, 0, stream>>>(out32, ln2_g, ln2_b, h2);
    gemm8_kernel<2,8><<<dim3(32*(4096/256)), gblk, 0, stream>>>(h2, w1_t, b1, nullptr, mid, ROWS, 4096, 1024);
    gemm8_kernel<3,4><<<dim3(64*(1024/256)), gblk, 0, stream>>>(mid, w2_t, b2, out32, outp, ROWS, 1024, 4096);
}

// Round 4
// 596.630 us; speedup vs baseline: 1.0571x; 1.0180x over previous
//
#include <hip/hip_runtime.h>
#include <hip/hip_bf16.h>

#define EMB 1024
#define NH 16
#define HD 64
#define BATCH 8
#define SEQ 1024
#define ROWS (BATCH*SEQ)   // 8192

typedef unsigned short ushort_t;
typedef __attribute__((ext_vector_type(8))) short bf16x8;
typedef __attribute__((ext_vector_type(4))) float f32x4;

__device__ __forceinline__ float bf2f(ushort_t u){
    union { unsigned int i; float f; } v; v.i = ((unsigned int)u) << 16; return v.f;
}
__device__ __forceinline__ ushort_t f2bf(float f){
    unsigned int u = __float_as_uint(f);
    unsigned int r = (u + 0x7FFFu + ((u >> 16) & 1u)) >> 16;
    return (ushort_t)r;
}
__device__ __forceinline__ void gload16(const ushort_t* g, ushort_t* l){
    __builtin_amdgcn_global_load_lds(
        (const __attribute__((address_space(1))) void*)g,
        (__attribute__((address_space(3))) void*)l,
        16, 0, 0);
}
// drain all in-flight global_load_lds + workgroup barrier (the ONLY sync per K-tile)
__device__ __forceinline__ void drain_barrier(){
    asm volatile("s_waitcnt vmcnt(0)" ::: "memory");
    __builtin_amdgcn_s_barrier();
    asm volatile("" ::: "memory");
}
// exact-erf GELU via A&S 7.1.26 (|err| < 1.5e-7)
__device__ __forceinline__ float gelu_f(float v){
    float x = fabsf(v) * 0.70710678118654752f;
    float t = __builtin_amdgcn_rcpf(1.0f + 0.3275911f * x);
    float poly = t*(0.254829592f + t*(-0.284496736f + t*(1.421413741f + t*(-1.453152027f + t*1.061405429f))));
    float erfa = 1.0f - poly * __expf(-x*x);
    float erfv = (v >= 0.f) ? erfa : -erfa;
    return 0.5f * v * (1.0f + erfv);
}

// ---------------- fused prep: LN1 (blocks 0..8191) + all 6 weight transposes ----------------
__global__ __launch_bounds__(256) void prep_kernel(const float* __restrict__ x,
                                                   const float* __restrict__ ln1_g,
                                                   const float* __restrict__ ln1_b,
                                                   ushort_t* __restrict__ h1,
                                                   const float* __restrict__ wq,
                                                   const float* __restrict__ wk,
                                                   const float* __restrict__ wv,
                                                   const float* __restrict__ w_proj,
                                                   const float* __restrict__ w1,
                                                   const float* __restrict__ w2,
                                                   ushort_t* __restrict__ wqkv_t,
                                                   ushort_t* __restrict__ wproj_t,
                                                   ushort_t* __restrict__ w1_t,
                                                   ushort_t* __restrict__ w2_t){
    int bid = blockIdx.x;
    int tid = threadIdx.x;
    if (bid < ROWS){
        __shared__ float ss[4], qq[4];
        __shared__ float mu_s, sc_s;
        const float* xr = x + (size_t)bid * EMB;
        float4 f = *(const float4*)(xr + tid*4);
        float v[4] = {f.x, f.y, f.z, f.w};
        float s = v[0]+v[1]+v[2]+v[3];
        float q = v[0]*v[0]+v[1]*v[1]+v[2]*v[2]+v[3]*v[3];
        #pragma unroll
        for (int o = 32; o > 0; o >>= 1){ s += __shfl_down(s, o); q += __shfl_down(q, o); }
        int wave = tid >> 6, lane = tid & 63;
        if (lane == 0){ ss[wave] = s; qq[wave] = q; }
        __syncthreads();
        if (tid == 0){
            float S = ss[0]+ss[1]+ss[2]+ss[3];
            float Q = qq[0]+qq[1]+qq[2]+qq[3];
            float mu = S * (1.0f/EMB);
            float var = Q * (1.0f/EMB) - mu*mu;
            mu_s = mu; sc_s = rsqrtf(var + 1e-5f);
        }
        __syncthreads();
        float mu = mu_s, sc = sc_s;
        float4 gu = *(const float4*)(ln1_g + tid*4);
        float4 bu = *(const float4*)(ln1_b + tid*4);
        ushort4 o4;
        o4.x = f2bf((v[0]-mu)*sc*gu.x + bu.x);
        o4.y = f2bf((v[1]-mu)*sc*gu.y + bu.y);
        o4.z = f2bf((v[2]-mu)*sc*gu.z + bu.z);
        o4.w = f2bf((v[3]-mu)*sc*gu.w + bu.w);
        *(ushort4*)(h1 + (size_t)bid*EMB + tid*4) = o4;
    } else {
        __shared__ ushort_t t[32][33];
        int j = bid - ROWS;
        const float* in; ushort_t* out; int K, N, bx, by;
        if (j < 3072){
            int which = j >> 10, jj = j & 1023;
            in = (which == 0) ? wq : (which == 1) ? wk : wv;
            out = wqkv_t + (size_t)which * 1024 * 1024;
            K = 1024; N = 1024; bx = jj & 31; by = jj >> 5;
        } else if (j < 4096){
            int jj = j - 3072;
            in = w_proj; out = wproj_t; K = 1024; N = 1024; bx = jj & 31; by = jj >> 5;
        } else if (j < 8192){
            int jj = j - 4096;
            in = w1; out = w1_t; K = 1024; N = 4096; bx = jj & 127; by = jj >> 7;
        } else {
            int jj = j - 8192;
            in = w2; out = w2_t; K = 4096; N = 1024; bx = jj & 31; by = jj >> 5;
        }
        int tx = tid & 31, ty = tid >> 5;
        #pragma unroll
        for (int r = 0; r < 4; ++r)
            t[ty + r*8][tx] = f2bf(in[(size_t)(by*32 + ty + r*8) * N + bx*32 + tx]);
        __syncthreads();
        #pragma unroll
        for (int r = 0; r < 4; ++r)
            out[(size_t)(bx*32 + ty + r*8) * K + by*32 + tx] = t[tx][ty + r*8];
    }
}

// ---------------- LayerNorm (row = 1024), f32 in -> bf16 out ----------------
__global__ __launch_bounds__(256) void ln_kernel(const float* __restrict__ xin,
                                                 const float* __restrict__ g,
                                                 const float* __restrict__ bia,
                                                 ushort_t* __restrict__ out){
    int row = blockIdx.x;
    int tid = threadIdx.x;
    const float* x = xin + (size_t)row * EMB;
    float4 f = *(const float4*)(x + tid*4);
    float v[4] = {f.x, f.y, f.z, f.w};
    float s = v[0]+v[1]+v[2]+v[3];
    float q = v[0]*v[0]+v[1]*v[1]+v[2]*v[2]+v[3]*v[3];
    #pragma unroll
    for (int o = 32; o > 0; o >>= 1){ s += __shfl_down(s, o); q += __shfl_down(q, o); }
    __shared__ float ss[4], qq[4];
    __shared__ float mu_s, sc_s;
    int wave = tid >> 6, lane = tid & 63;
    if (lane == 0){ ss[wave] = s; qq[wave] = q; }
    __syncthreads();
    if (tid == 0){
        float S = ss[0]+ss[1]+ss[2]+ss[3];
        float Q = qq[0]+qq[1]+qq[2]+qq[3];
        float mu = S * (1.0f/EMB);
        float var = Q * (1.0f/EMB) - mu*mu;
        mu_s = mu; sc_s = rsqrtf(var + 1e-5f);
    }
    __syncthreads();
    float mu = mu_s, sc = sc_s;
    float4 gu = *(const float4*)(g + tid*4);
    float4 bu = *(const float4*)(bia + tid*4);
    ushort4 o4;
    o4.x = f2bf((v[0]-mu)*sc*gu.x + bu.x);
    o4.y = f2bf((v[1]-mu)*sc*gu.y + bu.y);
    o4.z = f2bf((v[2]-mu)*sc*gu.z + bu.z);
    o4.w = f2bf((v[3]-mu)*sc*gu.w + bu.w);
    *(ushort4*)(out + (size_t)row*EMB + tid*4) = o4;
}

// ---------------- GEMM: 128x128 tile, 4 waves, fragment-major LDS, double-buffered, --------
// ---------------- ONE drain-barrier per K-tile, 2 blocks/CU ----------------
// Fragment-major LDS (proven 0 bank conflicts, rounds 2-3): frag f = fm*2+fk occupies the
// 1KB span [f*512 .. f*512+511] ushorts; lane l's b128 read at f*1024B + l*16 is the
// canonical conflict-free pattern. gload_lds dest is lane-linear; the per-lane GLOBAL
// source does the permutation: wave w stages frags {w, w+4, w+8, w+12} per operand.
// Schedule (deliberately minimal -- r2/r3 showed phase barriers cost ~30% at this size):
//   stage(next buf) at tile top -> full-tile prefetch lead; compute current buf;
//   single vmcnt(0)+s_barrier at tile end (covers RAW on next buf + WAR on cur).
// Latency absorption comes from 2 blocks/CU (64KB LDS) -- r0's mechanism, which r1-r3
// lost at 96KB. Compiler handles ds_read->MFMA lgkmcnt (near-optimal per m97 evidence).
// 16x16x32 MFMA: a/b-frag lane l = [m|n: l&15][k: (l>>4)*8..+8]; C/D col=l&15, row=(l>>4)*4+reg.
// MODE 0: plain -> bf16 | 1: +bias+resid -> f32 | 2: +bias+GELU -> bf16 | 3: +bias+resid -> f32
template<int MODE>
__global__ __launch_bounds__(256, 2) void gemm4_kernel(const ushort_t* __restrict__ A,
                                                       const ushort_t* __restrict__ Bt,
                                                       const float* __restrict__ bias,
                                                       const float* __restrict__ resid,
                                                       void* __restrict__ out,
                                                       int M, int N, int K){
    __shared__ ushort_t As[2][8192];   // 2 x 16 KB: 16 frags (8 m x 2 k) of 1KB
    __shared__ ushort_t Bs[2][8192];   // 2 x 16 KB: 16 frags (8 n x 2 k)

    int tid = threadIdx.x;
    int lane = tid & 63, w = tid >> 6;      // 4 waves
    int l15 = lane & 15, lq = lane >> 4;
    int wm = w >> 1, wn = w & 1;            // 2x2 wave grid; per-wave output 64x64
    int bid = blockIdx.x;
    int m0 = (bid & 63) * 128, n0 = (bid >> 6) * 128;

    f32x4 acc[4][4];
    #pragma unroll
    for (int i=0;i<4;i++)
        #pragma unroll
        for (int j=0;j<4;j++) acc[i][j] = (f32x4){0.f,0.f,0.f,0.f};

    // staging: wave w, round i stages frag fi = i*4+w  (fm = i*2 + (w>>1), fk = w&1)
    // lane l -> global [row0 + i*32 + l&15][k0 + (w&1)*32 + (l>>4)*8]
    const ushort_t* baseA = A  + (size_t)(m0 + (w>>1)*16 + l15)*K + (w&1)*32 + lq*8;
    const ushort_t* baseB = Bt + (size_t)(n0 + (w>>1)*16 + l15)*K + (w&1)*32 + lq*8;

    auto stage = [&](int buf, int k0){
        #pragma unroll
        for (int i = 0; i < 4; ++i){
            gload16(baseA + (size_t)(i*32)*K + k0, &As[buf][(i*4 + w)*512]);
            gload16(baseB + (size_t)(i*32)*K + k0, &Bs[buf][(i*4 + w)*512]);
        }
    };

    stage(0, 0);
    drain_barrier();

    int NT = K >> 6;
    for (int t = 0; t < NT; ++t){
        int cur = t & 1;
        if (t + 1 < NT) stage(cur ^ 1, (t + 1) << 6);   // full-tile prefetch lead

        const ushort_t* Ab = As[cur];
        const ushort_t* Bb = Bs[cur];
        bf16x8 af[2][4], bfr[2][4];
        #pragma unroll
        for (int kf=0;kf<2;kf++)
            #pragma unroll
            for (int i=0;i<4;i++){
                af[kf][i]  = *(const bf16x8*)&Ab[(((wm*4 + i)*2) + kf)*512 + lane*8];
                bfr[kf][i] = *(const bf16x8*)&Bb[(((wn*4 + i)*2) + kf)*512 + lane*8];
            }
        #pragma unroll
        for (int kf=0;kf<2;kf++)
            #pragma unroll
            for (int mi=0;mi<4;mi++)
                #pragma unroll
                for (int ni=0;ni<4;ni++)
                    acc[mi][ni] = __builtin_amdgcn_mfma_f32_16x16x32_bf16(af[kf][mi], bfr[kf][ni], acc[mi][ni], 0,0,0);

        if (t + 1 < NT) drain_barrier();   // single sync: prefetch landed (RAW) + WAR on cur
    }

    // epilogue: C/D col = n_base + ni*16 + l15, row = m_base + mi*16 + lq*4 + r
    int n_base = n0 + wn*64;
    int m_base = m0 + wm*64 + lq*4;
    float bn[4];
    #pragma unroll
    for (int ni=0;ni<4;ni++) bn[ni] = (MODE != 0) ? bias[n_base + ni*16 + l15] : 0.f;
    #pragma unroll
    for (int mi=0;mi<4;mi++){
        #pragma unroll
        for (int ni=0;ni<4;ni++){
            int n = n_base + ni*16 + l15;
            #pragma unroll
            for (int r=0;r<4;r++){
                int m = m_base + mi*16 + r;
                float v = acc[mi][ni][r];
                size_t idx = (size_t)m*N + n;
                if (MODE == 0){
                    ((ushort_t*)out)[idx] = f2bf(v);
                } else if (MODE == 1 || MODE == 3){
                    ((float*)out)[idx] = v + bn[ni] + resid[idx];
                } else {
                    ((ushort_t*)out)[idx] = f2bf(gelu_f(v + bn[ni]));
                }
            }
        }
    }
}

// ---------------- Flash attention (causal), S^T formulation ----------------
__global__ __launch_bounds__(256) void attn_kernel(const ushort_t* __restrict__ qkv,
                                                   ushort_t* __restrict__ attn_out){
    __shared__ ushort_t Qs[128*64];    // [q][d], gload chunk-swizzled
    __shared__ ushort_t Ks[64*64];     // [kv][d], gload chunk-swizzled
    __shared__ ushort_t Vts[64][72];   // V^T [d][kv], write-swizzled
    __shared__ ushort_t Ps[128*64];    // P [q][kv], XOR-slotted

    int tid = threadIdx.x;
    int lane = tid & 63, wave = tid >> 6;
    int quad = lane >> 4, l15 = lane & 15;
    int pair = blockIdx.x;         // 0..3
    int bh = blockIdx.y;           // 0..127
    int b = bh >> 4, h = bh & 15;
    size_t tb = (size_t)b * SEQ;

    int lr = lane >> 3, lch = lane & 7;   // gload lane decomposition
    int tr = tid >> 3;                    // V staging: rows 0..31
    int tc = (tid & 7) * 8;
    int sw_w = tid & 7;
    int sx = l15 & 7;                     // fragment-read chunk swizzle

    for (int t = 0; t < 2; ++t){
        int qi = t ? (7 - pair) : pair;

        {
            const ushort_t* gq = qkv + (size_t)(tb + qi*128 + wave*32 + lr)*3072 + h*64 + (lch^lr)*8;
            ushort_t* lq = &Qs[(wave*32)*64];
            #pragma unroll
            for (int p = 0; p < 4; ++p)
                gload16(gq + (size_t)(p*8)*3072, lq + p*8*64);
        }

        f32x4 o_acc[4][2];
        #pragma unroll
        for (int i=0;i<4;i++)
            #pragma unroll
            for (int j=0;j<2;j++) o_acc[i][j] = (f32x4){0.f,0.f,0.f,0.f};
        float m_st[2] = {-1e30f, -1e30f};
        float l_st[2] = {0.f, 0.f};

        int nj = 2*qi + 2;
        for (int j = 0; j < nj; ++j){
            {
                const ushort_t* gk = qkv + (size_t)(tb + j*64 + wave*16 + lr)*3072 + 1024 + h*64 + (lch^lr)*8;
                ushort_t* lk = &Ks[(wave*16)*64];
                gload16(gk, lk);
                gload16(gk + (size_t)8*3072, lk + 8*64);
            }
            #pragma unroll
            for (int p = 0; p < 2; ++p){
                int r = tr + p*32;
                bf16x8 vv = *(const bf16x8*)(qkv + (size_t)(tb + j*64 + r)*3072 + 2048 + h*64 + tc);
                int kcol = r ^ (sw_w << 3);
                #pragma unroll
                for (int c = 0; c < 8; ++c) Vts[tc + c][kcol] = (ushort_t)vv[c];
            }
            __syncthreads();

            // S^T[kv 64][q 32/wave] = K·Q^T
            f32x4 st[4][2];
            #pragma unroll
            for (int mt=0;mt<4;mt++)
                #pragma unroll
                for (int nt=0;nt<2;nt++) st[mt][nt] = (f32x4){0.f,0.f,0.f,0.f};
            #pragma unroll
            for (int kf = 0; kf < 2; ++kf){
                int ch = (kf*4 + quad) ^ sx;
                bf16x8 ak[4], bq[2];
                #pragma unroll
                for (int mt=0;mt<4;mt++) ak[mt] = *(const bf16x8*)&Ks[(mt*16 + l15)*64 + ch*8];
                #pragma unroll
                for (int nt=0;nt<2;nt++) bq[nt] = *(const bf16x8*)&Qs[(wave*32 + nt*16 + l15)*64 + ch*8];
                #pragma unroll
                for (int mt=0;mt<4;mt++)
                    #pragma unroll
                    for (int nt=0;nt<2;nt++)
                        st[mt][nt] = __builtin_amdgcn_mfma_f32_16x16x32_bf16(ak[mt], bq[nt], st[mt][nt], 0,0,0);
            }

            bool need_mask = (j >= 2*qi);
            #pragma unroll
            for (int mt=0;mt<4;mt++)
                #pragma unroll
                for (int nt=0;nt<2;nt++)
                    #pragma unroll
                    for (int r=0;r<4;r++){
                        float s = st[mt][nt][r] * 0.125f;
                        if (need_mask){
                            int kg = j*64 + mt*16 + quad*4 + r;
                            int qg = qi*128 + wave*32 + nt*16 + l15;
                            if (kg > qg) s = -1e30f;
                        }
                        st[mt][nt][r] = s;
                    }

            #pragma unroll
            for (int nt = 0; nt < 2; ++nt){
                float mx = st[0][nt][0];
                #pragma unroll
                for (int mt=0;mt<4;mt++)
                    #pragma unroll
                    for (int r=0;r<4;r++) mx = fmaxf(mx, st[mt][nt][r]);
                mx = fmaxf(mx, __shfl_xor(mx, 16));
                mx = fmaxf(mx, __shfl_xor(mx, 32));
                float mnew = fmaxf(m_st[nt], mx);
                float al = __expf(m_st[nt] - mnew);
                float ps = 0.f;
                #pragma unroll
                for (int mt=0;mt<4;mt++)
                    #pragma unroll
                    for (int r=0;r<4;r++){
                        float p = __expf(st[mt][nt][r] - mnew);
                        st[mt][nt][r] = p;
                        ps += p;
                    }
                ps += __shfl_xor(ps, 16);
                ps += __shfl_xor(ps, 32);
                l_st[nt] = l_st[nt]*al + ps;
                m_st[nt] = mnew;
                #pragma unroll
                for (int mtd=0;mtd<4;mtd++)
                    #pragma unroll
                    for (int r=0;r<4;r++) o_acc[mtd][nt][r] *= al;
                #pragma unroll
                for (int mt=0;mt<4;mt++){
                    int slot = (mt*2 + (quad>>1)) ^ sx;
                    ushort4 pk;
                    pk.x = f2bf(st[mt][nt][0]); pk.y = f2bf(st[mt][nt][1]);
                    pk.z = f2bf(st[mt][nt][2]); pk.w = f2bf(st[mt][nt][3]);
                    *(ushort4*)&Ps[(wave*32 + nt*16 + l15)*64 + slot*8 + (quad&1)*4] = pk;
                }
            }

            // O^T[d 64][q 32/wave] += V^T·P^T
            #pragma unroll
            for (int kf = 0; kf < 2; ++kf){
                bf16x8 av[4], bp[2];
                #pragma unroll
                for (int mtd=0;mtd<4;mtd++){
                    int d = mtd*16 + l15;
                    int col = (kf*32 + quad*8) ^ (((d >> 3) & 7) << 3);
                    av[mtd] = *(const bf16x8*)&Vts[d][col];
                }
                #pragma unroll
                for (int nt=0;nt<2;nt++){
                    int ch = (kf*4 + quad) ^ sx;
                    bp[nt] = *(const bf16x8*)&Ps[(wave*32 + nt*16 + l15)*64 + ch*8];
                }
                #pragma unroll
                for (int mtd=0;mtd<4;mtd++)
                    #pragma unroll
                    for (int nt=0;nt<2;nt++)
                        o_acc[mtd][nt] = __builtin_amdgcn_mfma_f32_16x16x32_bf16(av[mtd], bp[nt], o_acc[mtd][nt], 0,0,0);
            }
            __syncthreads();
        }

        #pragma unroll
        for (int nt = 0; nt < 2; ++nt){
            float inv = 1.0f / l_st[nt];
            size_t tok = tb + qi*128 + wave*32 + nt*16 + l15;
            #pragma unroll
            for (int mtd = 0; mtd < 4; ++mtd){
                ushort4 ok;
                ok.x = f2bf(o_acc[mtd][nt][0]*inv); ok.y = f2bf(o_acc[mtd][nt][1]*inv);
                ok.z = f2bf(o_acc[mtd][nt][2]*inv); ok.w = f2bf(o_acc[mtd][nt][3]*inv);
                *(ushort4*)(attn_out + tok*EMB + h*64 + mtd*16 + quad*4) = ok;
            }
        }
    }
}

extern "C" void kernel_launch(void* const* d_in, const int* in_sizes, int n_in,
                              void* d_out, int out_size, void* d_ws, size_t ws_size,
                              hipStream_t stream){
    const float* x      = (const float*)d_in[0];
    const float* ln1_g  = (const float*)d_in[1];
    const float* ln1_b  = (const float*)d_in[2];
    const float* wq     = (const float*)d_in[3];
    const float* wk     = (const float*)d_in[4];
    const float* wv     = (const float*)d_in[5];
    const float* w_proj = (const float*)d_in[6];
    const float* b_proj = (const float*)d_in[7];
    const float* ln2_g  = (const float*)d_in[8];
    const float* ln2_b  = (const float*)d_in[9];
    const float* w1     = (const float*)d_in[10];
    const float* b1     = (const float*)d_in[11];
    const float* w2     = (const float*)d_in[12];
    const float* b2     = (const float*)d_in[13];
    float* outp = (float*)d_out;

    char* ws = (char*)d_ws;
    size_t off = 0;
    auto alloc = [&](size_t bytes)->char*{ char* p = ws + off; off += (bytes + 255) & ~255ULL; return p; };
    ushort_t* wqkv_t = (ushort_t*)alloc((size_t)3072*1024*2);
    ushort_t* wproj_t= (ushort_t*)alloc((size_t)1024*1024*2);
    ushort_t* w1_t   = (ushort_t*)alloc((size_t)4096*1024*2);
    ushort_t* w2_t   = (ushort_t*)alloc((size_t)1024*4096*2);
    ushort_t* qkv    = (ushort_t*)alloc((size_t)ROWS*3072*2);
    ushort_t* hbuf   = (ushort_t*)alloc((size_t)ROWS*1024*2);
    float*    out32  = (float*)  alloc((size_t)ROWS*1024*4);
    ushort_t* mid    = (ushort_t*)alloc((size_t)ROWS*4096*2);
    ushort_t* h1 = hbuf;
    ushort_t* attn = hbuf;   // h1 dead after qkv GEMM
    ushort_t* h2 = qkv;      // qkv dead after attention

    dim3 blk(256);
    // blocks: 8192 LN1 rows + 3072 (wq/wk/wv) + 1024 (wproj) + 4096 (w1) + 4096 (w2)
    prep_kernel<<<dim3(20480), blk, 0, stream>>>(x, ln1_g, ln1_b, h1,
                                                 wq, wk, wv, w_proj, w1, w2,
                                                 wqkv_t, wproj_t, w1_t, w2_t);
    // grids: 64 m-tiles x (N/128) n-tiles -> 1536 / 512 / 2048 / 512 (all multiples of 256)
    gemm4_kernel<0><<<dim3(64*(3072/128)), blk, 0, stream>>>(h1, wqkv_t, nullptr, nullptr, qkv, ROWS, 3072, 1024);
    attn_kernel<<<dim3(4,128), blk, 0, stream>>>(qkv, attn);
    gemm4_kernel<1><<<dim3(64*(1024/128)), blk, 0, stream>>>(attn, wproj_t, b_proj, x, out32, ROWS, 1024, 1024);
    ln_kernel<<<ROWS, blk, 0, stream>>>(out32, ln2_g, ln2_b, h2);
    gemm4_kernel<2><<<dim3(64*(4096/128)), blk, 0, stream>>>(h2, w1_t, b1, nullptr, mid, ROWS, 4096, 1024);
    gemm4_kernel<3><<<dim3(64*(1024/128)), blk, 0, stream>>>(mid, w2_t, b2, out32, outp, ROWS, 1024, 4096);
}

// Round 5
// 510.583 us; speedup vs baseline: 1.2353x; 1.1685x over previous
//
#include <hip/hip_runtime.h>
#include <hip/hip_bf16.h>

#define EMB 1024
#define NH 16
#define HD 64
#define BATCH 8
#define SEQ 1024
#define ROWS (BATCH*SEQ)   // 8192

typedef unsigned short ushort_t;
typedef __attribute__((ext_vector_type(8))) short bf16x8;
typedef __attribute__((ext_vector_type(4))) float f32x4;
typedef __attribute__((ext_vector_type(16))) float f32x16;

__device__ __forceinline__ float bf2f(ushort_t u){
    union { unsigned int i; float f; } v; v.i = ((unsigned int)u) << 16; return v.f;
}
__device__ __forceinline__ ushort_t f2bf(float f){
    unsigned int u = __float_as_uint(f);
    unsigned int r = (u + 0x7FFFu + ((u >> 16) & 1u)) >> 16;
    return (ushort_t)r;
}
__device__ __forceinline__ void gload16(const ushort_t* g, ushort_t* l){
    __builtin_amdgcn_global_load_lds(
        (const __attribute__((address_space(1))) void*)g,
        (__attribute__((address_space(3))) void*)l,
        16, 0, 0);
}
// exact-erf GELU via A&S 7.1.26 (|err| < 1.5e-7)
__device__ __forceinline__ float gelu_f(float v){
    float x = fabsf(v) * 0.70710678118654752f;
    float t = __builtin_amdgcn_rcpf(1.0f + 0.3275911f * x);
    float poly = t*(0.254829592f + t*(-0.284496736f + t*(1.421413741f + t*(-1.453152027f + t*1.061405429f))));
    float erfa = 1.0f - poly * __expf(-x*x);
    float erfv = (v >= 0.f) ? erfa : -erfa;
    return 0.5f * v * (1.0f + erfv);
}

// ---------------- fused prep: LN1 (blocks 0..8191) + all 6 weight transposes ----------------
__global__ __launch_bounds__(256) void prep_kernel(const float* __restrict__ x,
                                                   const float* __restrict__ ln1_g,
                                                   const float* __restrict__ ln1_b,
                                                   ushort_t* __restrict__ h1,
                                                   const float* __restrict__ wq,
                                                   const float* __restrict__ wk,
                                                   const float* __restrict__ wv,
                                                   const float* __restrict__ w_proj,
                                                   const float* __restrict__ w1,
                                                   const float* __restrict__ w2,
                                                   ushort_t* __restrict__ wqkv_t,
                                                   ushort_t* __restrict__ wproj_t,
                                                   ushort_t* __restrict__ w1_t,
                                                   ushort_t* __restrict__ w2_t){
    int bid = blockIdx.x;
    int tid = threadIdx.x;
    if (bid < ROWS){
        __shared__ float ss[4], qq[4];
        __shared__ float mu_s, sc_s;
        const float* xr = x + (size_t)bid * EMB;
        float4 f = *(const float4*)(xr + tid*4);
        float v[4] = {f.x, f.y, f.z, f.w};
        float s = v[0]+v[1]+v[2]+v[3];
        float q = v[0]*v[0]+v[1]*v[1]+v[2]*v[2]+v[3]*v[3];
        #pragma unroll
        for (int o = 32; o > 0; o >>= 1){ s += __shfl_down(s, o); q += __shfl_down(q, o); }
        int wave = tid >> 6, lane = tid & 63;
        if (lane == 0){ ss[wave] = s; qq[wave] = q; }
        __syncthreads();
        if (tid == 0){
            float S = ss[0]+ss[1]+ss[2]+ss[3];
            float Q = qq[0]+qq[1]+qq[2]+qq[3];
            float mu = S * (1.0f/EMB);
            float var = Q * (1.0f/EMB) - mu*mu;
            mu_s = mu; sc_s = rsqrtf(var + 1e-5f);
        }
        __syncthreads();
        float mu = mu_s, sc = sc_s;
        float4 gu = *(const float4*)(ln1_g + tid*4);
        float4 bu = *(const float4*)(ln1_b + tid*4);
        ushort4 o4;
        o4.x = f2bf((v[0]-mu)*sc*gu.x + bu.x);
        o4.y = f2bf((v[1]-mu)*sc*gu.y + bu.y);
        o4.z = f2bf((v[2]-mu)*sc*gu.z + bu.z);
        o4.w = f2bf((v[3]-mu)*sc*gu.w + bu.w);
        *(ushort4*)(h1 + (size_t)bid*EMB + tid*4) = o4;
    } else {
        __shared__ ushort_t t[32][33];
        int j = bid - ROWS;
        const float* in; ushort_t* out; int K, N, bx, by;
        if (j < 3072){
            int which = j >> 10, jj = j & 1023;
            in = (which == 0) ? wq : (which == 1) ? wk : wv;
            out = wqkv_t + (size_t)which * 1024 * 1024;
            K = 1024; N = 1024; bx = jj & 31; by = jj >> 5;
        } else if (j < 4096){
            int jj = j - 3072;
            in = w_proj; out = wproj_t; K = 1024; N = 1024; bx = jj & 31; by = jj >> 5;
        } else if (j < 8192){
            int jj = j - 4096;
            in = w1; out = w1_t; K = 1024; N = 4096; bx = jj & 127; by = jj >> 7;
        } else {
            int jj = j - 8192;
            in = w2; out = w2_t; K = 4096; N = 1024; bx = jj & 31; by = jj >> 5;
        }
        int tx = tid & 31, ty = tid >> 5;
        #pragma unroll
        for (int r = 0; r < 4; ++r)
            t[ty + r*8][tx] = f2bf(in[(size_t)(by*32 + ty + r*8) * N + bx*32 + tx]);
        __syncthreads();
        #pragma unroll
        for (int r = 0; r < 4; ++r)
            out[(size_t)(bx*32 + ty + r*8) * K + by*32 + tx] = t[tx][ty + r*8];
    }
}

// ---------------- LayerNorm (row = 1024), f32 in -> bf16 out ----------------
__global__ __launch_bounds__(256) void ln_kernel(const float* __restrict__ xin,
                                                 const float* __restrict__ g,
                                                 const float* __restrict__ bia,
                                                 ushort_t* __restrict__ out){
    int row = blockIdx.x;
    int tid = threadIdx.x;
    const float* x = xin + (size_t)row * EMB;
    float4 f = *(const float4*)(x + tid*4);
    float v[4] = {f.x, f.y, f.z, f.w};
    float s = v[0]+v[1]+v[2]+v[3];
    float q = v[0]*v[0]+v[1]*v[1]+v[2]*v[2]+v[3]*v[3];
    #pragma unroll
    for (int o = 32; o > 0; o >>= 1){ s += __shfl_down(s, o); q += __shfl_down(q, o); }
    __shared__ float ss[4], qq[4];
    __shared__ float mu_s, sc_s;
    int wave = tid >> 6, lane = tid & 63;
    if (lane == 0){ ss[wave] = s; qq[wave] = q; }
    __syncthreads();
    if (tid == 0){
        float S = ss[0]+ss[1]+ss[2]+ss[3];
        float Q = qq[0]+qq[1]+qq[2]+qq[3];
        float mu = S * (1.0f/EMB);
        float var = Q * (1.0f/EMB) - mu*mu;
        mu_s = mu; sc_s = rsqrtf(var + 1e-5f);
    }
    __syncthreads();
    float mu = mu_s, sc = sc_s;
    float4 gu = *(const float4*)(g + tid*4);
    float4 bu = *(const float4*)(bia + tid*4);
    ushort4 o4;
    o4.x = f2bf((v[0]-mu)*sc*gu.x + bu.x);
    o4.y = f2bf((v[1]-mu)*sc*gu.y + bu.y);
    o4.z = f2bf((v[2]-mu)*sc*gu.z + bu.z);
    o4.w = f2bf((v[3]-mu)*sc*gu.w + bu.w);
    *(ushort4*)(out + (size_t)row*EMB + tid*4) = o4;
}

// ---------------- GEMM: (MF*64) x 128 tile, 32x32x16 MFMA, XOR-swizzled LDS ----------------
// EXACT r0 structure (the empirically best: staged-bytes/8.5TB/s fits all 4 gemm times).
// MF = m-frags(32 rows) per wave: MF=2 -> BM=128 (r0-exact), MF=4 -> BM=256 (halves B staging).
// Single-buffered LDS, 2x __syncthreads per K-tile; latency hidden by 2+ resident blocks/CU.
// LDS chunk c (16B) of row r holds global chunk c ^ (r&7) -> conflict-light b128 reads (2-way,
// free per m136). 1-D grid, mt = bid & (MT-1) => same-m blocks share an XCD (L2 A-reuse).
// MODE 0: plain -> bf16 | 1: +bias+resid -> f32 | 2: +bias+GELU -> bf16 | 3: +bias+resid -> f32
template<int MODE, int MF>
__global__ __launch_bounds__(256) void gemm_kernel(const ushort_t* __restrict__ A,
                                                   const ushort_t* __restrict__ Bt,
                                                   const float* __restrict__ bias,
                                                   const float* __restrict__ resid,
                                                   void* __restrict__ out,
                                                   int M, int N, int K){
    constexpr int BM  = MF * 64;
    constexpr int MT_ = 8192 / BM;       // 32 or 64 m-tiles
    __shared__ ushort_t As[BM*64];       // MF=2: 16KB, MF=4: 32KB
    __shared__ ushort_t Bs[128*64];      // 16KB
    int tid = threadIdx.x;
    int lane = tid & 63, wave = tid >> 6;
    int l31 = lane & 31, half = lane >> 5;
    int wm = wave >> 1, wn = wave & 1;   // 2x2 wave grid; per-wave out (MF*32) x 64
    int bid = blockIdx.x;
    int m0 = (bid & (MT_-1)) * BM, n0 = (bid / MT_) * 128;

    f32x16 acc[MF][2];
    #pragma unroll
    for (int i=0;i<MF;i++)
        #pragma unroll
        for (int j=0;j<2;j++)
            #pragma unroll
            for (int r=0;r<16;r++) acc[i][j][r] = 0.f;

    int lr  = lane >> 3;        // row within 8-row group
    int lch = lane & 7;         // destination LDS chunk
    const ushort_t* gA = A  + (size_t)(m0 + wave*(BM/4) + lr)*K + (lch ^ lr)*8;
    const ushort_t* gB = Bt + (size_t)(n0 + wave*32 + lr)*K + (lch ^ lr)*8;
    ushort_t* lA = &As[(wave*(BM/4))*64];
    ushort_t* lB = &Bs[(wave*32)*64];
    int sx = lane & 7;          // fragment-read swizzle (row&7 == lane&7)

    for (int k0 = 0; k0 < K; k0 += 64){
        #pragma unroll
        for (int i = 0; i < BM/32; ++i)               // A rows: BM/4 per wave, 8 per instr
            gload16(gA + (size_t)(i*8)*K + k0, lA + i*8*64);
        #pragma unroll
        for (int i = 0; i < 4; ++i)
            gload16(gB + (size_t)(i*8)*K + k0, lB + i*8*64);
        __syncthreads();
        #pragma unroll
        for (int s = 0; s < 4; ++s){
            int ch = ((s<<1) | half) ^ sx;
            bf16x8 af[MF], bfr[2];
            #pragma unroll
            for (int i=0;i<MF;i++) af[i]  = *(const bf16x8*)&As[(wm*(BM/2) + i*32 + l31)*64 + ch*8];
            #pragma unroll
            for (int j=0;j<2;j++)  bfr[j] = *(const bf16x8*)&Bs[(wn*64 + j*32 + l31)*64 + ch*8];
            #pragma unroll
            for (int i=0;i<MF;i++)
                #pragma unroll
                for (int j=0;j<2;j++)
                    acc[i][j] = __builtin_amdgcn_mfma_f32_32x32x16_bf16(af[i], bfr[j], acc[i][j], 0,0,0);
        }
        __syncthreads();
    }

    // C/D layout (32x32): col = lane&31, row = (reg&3) + 8*(reg>>2) + 4*(lane>>5)
    int rowoff = 4*half;
    #pragma unroll
    for (int i=0;i<MF;i++){
        #pragma unroll
        for (int j=0;j<2;j++){
            int n = n0 + wn*64 + j*32 + l31;
            #pragma unroll
            for (int reg=0; reg<16; ++reg){
                int m = m0 + wm*(BM/2) + i*32 + (reg&3) + 8*(reg>>2) + rowoff;
                float v = acc[i][j][reg];
                size_t idx = (size_t)m*N + n;
                if (MODE == 0){
                    ((ushort_t*)out)[idx] = f2bf(v);
                } else if (MODE == 1){
                    v += bias[n] + resid[idx];
                    ((float*)out)[idx] = v;
                } else if (MODE == 2){
                    v += bias[n];
                    ((ushort_t*)out)[idx] = f2bf(gelu_f(v));
                } else {
                    v += bias[n] + resid[idx];
                    ((float*)out)[idx] = v;
                }
            }
        }
    }
}

// ---------------- Flash attention (causal), S^T formulation ----------------
__global__ __launch_bounds__(256) void attn_kernel(const ushort_t* __restrict__ qkv,
                                                   ushort_t* __restrict__ attn_out){
    __shared__ ushort_t Qs[128*64];    // [q][d], gload chunk-swizzled
    __shared__ ushort_t Ks[64*64];     // [kv][d], gload chunk-swizzled
    __shared__ ushort_t Vts[64][72];   // V^T [d][kv], write-swizzled
    __shared__ ushort_t Ps[128*64];    // P [q][kv], XOR-slotted

    int tid = threadIdx.x;
    int lane = tid & 63, wave = tid >> 6;
    int quad = lane >> 4, l15 = lane & 15;
    int pair = blockIdx.x;         // 0..3
    int bh = blockIdx.y;           // 0..127
    int b = bh >> 4, h = bh & 15;
    size_t tb = (size_t)b * SEQ;

    int lr = lane >> 3, lch = lane & 7;   // gload lane decomposition
    int tr = tid >> 3;                    // V staging: rows 0..31
    int tc = (tid & 7) * 8;
    int sw_w = tid & 7;
    int sx = l15 & 7;                     // fragment-read chunk swizzle

    for (int t = 0; t < 2; ++t){
        int qi = t ? (7 - pair) : pair;

        {
            const ushort_t* gq = qkv + (size_t)(tb + qi*128 + wave*32 + lr)*3072 + h*64 + (lch^lr)*8;
            ushort_t* lq = &Qs[(wave*32)*64];
            #pragma unroll
            for (int p = 0; p < 4; ++p)
                gload16(gq + (size_t)(p*8)*3072, lq + p*8*64);
        }

        f32x4 o_acc[4][2];
        #pragma unroll
        for (int i=0;i<4;i++)
            #pragma unroll
            for (int j=0;j<2;j++) o_acc[i][j] = (f32x4){0.f,0.f,0.f,0.f};
        float m_st[2] = {-1e30f, -1e30f};
        float l_st[2] = {0.f, 0.f};

        int nj = 2*qi + 2;
        for (int j = 0; j < nj; ++j){
            {
                const ushort_t* gk = qkv + (size_t)(tb + j*64 + wave*16 + lr)*3072 + 1024 + h*64 + (lch^lr)*8;
                ushort_t* lk = &Ks[(wave*16)*64];
                gload16(gk, lk);
                gload16(gk + (size_t)8*3072, lk + 8*64);
            }
            #pragma unroll
            for (int p = 0; p < 2; ++p){
                int r = tr + p*32;
                bf16x8 vv = *(const bf16x8*)(qkv + (size_t)(tb + j*64 + r)*3072 + 2048 + h*64 + tc);
                int kcol = r ^ (sw_w << 3);
                #pragma unroll
                for (int c = 0; c < 8; ++c) Vts[tc + c][kcol] = (ushort_t)vv[c];
            }
            __syncthreads();

            // S^T[kv 64][q 32/wave] = K·Q^T
            f32x4 st[4][2];
            #pragma unroll
            for (int mt=0;mt<4;mt++)
                #pragma unroll
                for (int nt=0;nt<2;nt++) st[mt][nt] = (f32x4){0.f,0.f,0.f,0.f};
            #pragma unroll
            for (int kf = 0; kf < 2; ++kf){
                int ch = (kf*4 + quad) ^ sx;
                bf16x8 ak[4], bq[2];
                #pragma unroll
                for (int mt=0;mt<4;mt++) ak[mt] = *(const bf16x8*)&Ks[(mt*16 + l15)*64 + ch*8];
                #pragma unroll
                for (int nt=0;nt<2;nt++) bq[nt] = *(const bf16x8*)&Qs[(wave*32 + nt*16 + l15)*64 + ch*8];
                #pragma unroll
                for (int mt=0;mt<4;mt++)
                    #pragma unroll
                    for (int nt=0;nt<2;nt++)
                        st[mt][nt] = __builtin_amdgcn_mfma_f32_16x16x32_bf16(ak[mt], bq[nt], st[mt][nt], 0,0,0);
            }

            bool need_mask = (j >= 2*qi);
            #pragma unroll
            for (int mt=0;mt<4;mt++)
                #pragma unroll
                for (int nt=0;nt<2;nt++)
                    #pragma unroll
                    for (int r=0;r<4;r++){
                        float s = st[mt][nt][r] * 0.125f;
                        if (need_mask){
                            int kg = j*64 + mt*16 + quad*4 + r;
                            int qg = qi*128 + wave*32 + nt*16 + l15;
                            if (kg > qg) s = -1e30f;
                        }
                        st[mt][nt][r] = s;
                    }

            #pragma unroll
            for (int nt = 0; nt < 2; ++nt){
                float mx = st[0][nt][0];
                #pragma unroll
                for (int mt=0;mt<4;mt++)
                    #pragma unroll
                    for (int r=0;r<4;r++) mx = fmaxf(mx, st[mt][nt][r]);
                mx = fmaxf(mx, __shfl_xor(mx, 16));
                mx = fmaxf(mx, __shfl_xor(mx, 32));
                float mnew = fmaxf(m_st[nt], mx);
                float al = __expf(m_st[nt] - mnew);
                float ps = 0.f;
                #pragma unroll
                for (int mt=0;mt<4;mt++)
                    #pragma unroll
                    for (int r=0;r<4;r++){
                        float p = __expf(st[mt][nt][r] - mnew);
                        st[mt][nt][r] = p;
                        ps += p;
                    }
                ps += __shfl_xor(ps, 16);
                ps += __shfl_xor(ps, 32);
                l_st[nt] = l_st[nt]*al + ps;
                m_st[nt] = mnew;
                #pragma unroll
                for (int mtd=0;mtd<4;mtd++)
                    #pragma unroll
                    for (int r=0;r<4;r++) o_acc[mtd][nt][r] *= al;
                #pragma unroll
                for (int mt=0;mt<4;mt++){
                    int slot = (mt*2 + (quad>>1)) ^ sx;
                    ushort4 pk;
                    pk.x = f2bf(st[mt][nt][0]); pk.y = f2bf(st[mt][nt][1]);
                    pk.z = f2bf(st[mt][nt][2]); pk.w = f2bf(st[mt][nt][3]);
                    *(ushort4*)&Ps[(wave*32 + nt*16 + l15)*64 + slot*8 + (quad&1)*4] = pk;
                }
            }

            // O^T[d 64][q 32/wave] += V^T·P^T
            #pragma unroll
            for (int kf = 0; kf < 2; ++kf){
                bf16x8 av[4], bp[2];
                #pragma unroll
                for (int mtd=0;mtd<4;mtd++){
                    int d = mtd*16 + l15;
                    int col = (kf*32 + quad*8) ^ (((d >> 3) & 7) << 3);
                    av[mtd] = *(const bf16x8*)&Vts[d][col];
                }
                #pragma unroll
                for (int nt=0;nt<2;nt++){
                    int ch = (kf*4 + quad) ^ sx;
                    bp[nt] = *(const bf16x8*)&Ps[(wave*32 + nt*16 + l15)*64 + ch*8];
                }
                #pragma unroll
                for (int mtd=0;mtd<4;mtd++)
                    #pragma unroll
                    for (int nt=0;nt<2;nt++)
                        o_acc[mtd][nt] = __builtin_amdgcn_mfma_f32_16x16x32_bf16(av[mtd], bp[nt], o_acc[mtd][nt], 0,0,0);
            }
            __syncthreads();
        }

        #pragma unroll
        for (int nt = 0; nt < 2; ++nt){
            float inv = 1.0f / l_st[nt];
            size_t tok = tb + qi*128 + wave*32 + nt*16 + l15;
            #pragma unroll
            for (int mtd = 0; mtd < 4; ++mtd){
                ushort4 ok;
                ok.x = f2bf(o_acc[mtd][nt][0]*inv); ok.y = f2bf(o_acc[mtd][nt][1]*inv);
                ok.z = f2bf(o_acc[mtd][nt][2]*inv); ok.w = f2bf(o_acc[mtd][nt][3]*inv);
                *(ushort4*)(attn_out + tok*EMB + h*64 + mtd*16 + quad*4) = ok;
            }
        }
    }
}

extern "C" void kernel_launch(void* const* d_in, const int* in_sizes, int n_in,
                              void* d_out, int out_size, void* d_ws, size_t ws_size,
                              hipStream_t stream){
    const float* x      = (const float*)d_in[0];
    const float* ln1_g  = (const float*)d_in[1];
    const float* ln1_b  = (const float*)d_in[2];
    const float* wq     = (const float*)d_in[3];
    const float* wk     = (const float*)d_in[4];
    const float* wv     = (const float*)d_in[5];
    const float* w_proj = (const float*)d_in[6];
    const float* b_proj = (const float*)d_in[7];
    const float* ln2_g  = (const float*)d_in[8];
    const float* ln2_b  = (const float*)d_in[9];
    const float* w1     = (const float*)d_in[10];
    const float* b1     = (const float*)d_in[11];
    const float* w2     = (const float*)d_in[12];
    const float* b2     = (const float*)d_in[13];
    float* outp = (float*)d_out;

    char* ws = (char*)d_ws;
    size_t off = 0;
    auto alloc = [&](size_t bytes)->char*{ char* p = ws + off; off += (bytes + 255) & ~255ULL; return p; };
    ushort_t* wqkv_t = (ushort_t*)alloc((size_t)3072*1024*2);
    ushort_t* wproj_t= (ushort_t*)alloc((size_t)1024*1024*2);
    ushort_t* w1_t   = (ushort_t*)alloc((size_t)4096*1024*2);
    ushort_t* w2_t   = (ushort_t*)alloc((size_t)1024*4096*2);
    ushort_t* qkv    = (ushort_t*)alloc((size_t)ROWS*3072*2);
    ushort_t* hbuf   = (ushort_t*)alloc((size_t)ROWS*1024*2);
    float*    out32  = (float*)  alloc((size_t)ROWS*1024*4);
    ushort_t* mid    = (ushort_t*)alloc((size_t)ROWS*4096*2);
    ushort_t* h1 = hbuf;
    ushort_t* attn = hbuf;   // h1 dead after qkv GEMM
    ushort_t* h2 = qkv;      // qkv dead after attention

    dim3 blk(256);
    // blocks: 8192 LN1 rows + 3072 (wq/wk/wv) + 1024 (wproj) + 4096 (w1) + 4096 (w2)
    prep_kernel<<<dim3(20480), blk, 0, stream>>>(x, ln1_g, ln1_b, h1,
                                                 wq, wk, wv, w_proj, w1, w2,
                                                 wqkv_t, wproj_t, w1_t, w2_t);
    // QKV: BM=256 -> 32x24 = 768 blocks (3/CU); B staging halved vs r0
    gemm_kernel<0,4><<<dim3(32*(3072/128)), blk, 0, stream>>>(h1, wqkv_t, nullptr, nullptr, qkv, ROWS, 3072, 1024);
    attn_kernel<<<dim3(4,128), blk, 0, stream>>>(qkv, attn);
    // proj: N=1024 -> keep BM=128 (grid 512 = 2/CU; BM=256 would leave 256 = 1/CU)
    gemm_kernel<1,2><<<dim3(64*(1024/128)), blk, 0, stream>>>(attn, wproj_t, b_proj, x, out32, ROWS, 1024, 1024);
    ln_kernel<<<ROWS, blk, 0, stream>>>(out32, ln2_g, ln2_b, h2);
    // MLP1: BM=256 -> 32x32 = 1024 blocks (4/CU); B staging halved vs r0
    gemm_kernel<2,4><<<dim3(32*(4096/128)), blk, 0, stream>>>(h2, w1_t, b1, nullptr, mid, ROWS, 4096, 1024);
    // MLP2: N=1024 -> keep BM=128 (grid 512 = 2/CU)
    gemm_kernel<3,2><<<dim3(64*(1024/128)), blk, 0, stream>>>(mid, w2_t, b2, out32, outp, ROWS, 1024, 4096);
}

// Round 6
// 489.938 us; speedup vs baseline: 1.2873x; 1.0421x over previous
//
#include <hip/hip_runtime.h>
#include <hip/hip_bf16.h>

#define EMB 1024
#define NH 16
#define HD 64
#define BATCH 8
#define SEQ 1024
#define ROWS (BATCH*SEQ)   // 8192

typedef unsigned short ushort_t;
typedef __attribute__((ext_vector_type(8))) short bf16x8;
typedef __attribute__((ext_vector_type(4))) float f32x4;
typedef __attribute__((ext_vector_type(16))) float f32x16;

__device__ __forceinline__ float bf2f(ushort_t u){
    union { unsigned int i; float f; } v; v.i = ((unsigned int)u) << 16; return v.f;
}
__device__ __forceinline__ ushort_t f2bf(float f){
    unsigned int u = __float_as_uint(f);
    unsigned int r = (u + 0x7FFFu + ((u >> 16) & 1u)) >> 16;
    return (ushort_t)r;
}
__device__ __forceinline__ void gload16(const ushort_t* g, ushort_t* l){
    __builtin_amdgcn_global_load_lds(
        (const __attribute__((address_space(1))) void*)g,
        (__attribute__((address_space(3))) void*)l,
        16, 0, 0);
}
// exact-erf GELU via A&S 7.1.26 (|err| < 1.5e-7)
__device__ __forceinline__ float gelu_f(float v){
    float x = fabsf(v) * 0.70710678118654752f;
    float t = __builtin_amdgcn_rcpf(1.0f + 0.3275911f * x);
    float poly = t*(0.254829592f + t*(-0.284496736f + t*(1.421413741f + t*(-1.453152027f + t*1.061405429f))));
    float erfa = 1.0f - poly * __expf(-x*x);
    float erfv = (v >= 0.f) ? erfa : -erfa;
    return 0.5f * v * (1.0f + erfv);
}

// ---------------- fused prep: LN1 (blocks 0..8191) + all 6 weight transposes ----------------
__global__ __launch_bounds__(256) void prep_kernel(const float* __restrict__ x,
                                                   const float* __restrict__ ln1_g,
                                                   const float* __restrict__ ln1_b,
                                                   ushort_t* __restrict__ h1,
                                                   const float* __restrict__ wq,
                                                   const float* __restrict__ wk,
                                                   const float* __restrict__ wv,
                                                   const float* __restrict__ w_proj,
                                                   const float* __restrict__ w1,
                                                   const float* __restrict__ w2,
                                                   ushort_t* __restrict__ wqkv_t,
                                                   ushort_t* __restrict__ wproj_t,
                                                   ushort_t* __restrict__ w1_t,
                                                   ushort_t* __restrict__ w2_t){
    int bid = blockIdx.x;
    int tid = threadIdx.x;
    if (bid < ROWS){
        __shared__ float ss[4], qq[4];
        __shared__ float mu_s, sc_s;
        const float* xr = x + (size_t)bid * EMB;
        float4 f = *(const float4*)(xr + tid*4);
        float v[4] = {f.x, f.y, f.z, f.w};
        float s = v[0]+v[1]+v[2]+v[3];
        float q = v[0]*v[0]+v[1]*v[1]+v[2]*v[2]+v[3]*v[3];
        #pragma unroll
        for (int o = 32; o > 0; o >>= 1){ s += __shfl_down(s, o); q += __shfl_down(q, o); }
        int wave = tid >> 6, lane = tid & 63;
        if (lane == 0){ ss[wave] = s; qq[wave] = q; }
        __syncthreads();
        if (tid == 0){
            float S = ss[0]+ss[1]+ss[2]+ss[3];
            float Q = qq[0]+qq[1]+qq[2]+qq[3];
            float mu = S * (1.0f/EMB);
            float var = Q * (1.0f/EMB) - mu*mu;
            mu_s = mu; sc_s = rsqrtf(var + 1e-5f);
        }
        __syncthreads();
        float mu = mu_s, sc = sc_s;
        float4 gu = *(const float4*)(ln1_g + tid*4);
        float4 bu = *(const float4*)(ln1_b + tid*4);
        ushort4 o4;
        o4.x = f2bf((v[0]-mu)*sc*gu.x + bu.x);
        o4.y = f2bf((v[1]-mu)*sc*gu.y + bu.y);
        o4.z = f2bf((v[2]-mu)*sc*gu.z + bu.z);
        o4.w = f2bf((v[3]-mu)*sc*gu.w + bu.w);
        *(ushort4*)(h1 + (size_t)bid*EMB + tid*4) = o4;
    } else {
        __shared__ ushort_t t[32][33];
        int j = bid - ROWS;
        const float* in; ushort_t* out; int K, N, bx, by;
        if (j < 3072){
            int which = j >> 10, jj = j & 1023;
            in = (which == 0) ? wq : (which == 1) ? wk : wv;
            out = wqkv_t + (size_t)which * 1024 * 1024;
            K = 1024; N = 1024; bx = jj & 31; by = jj >> 5;
        } else if (j < 4096){
            int jj = j - 3072;
            in = w_proj; out = wproj_t; K = 1024; N = 1024; bx = jj & 31; by = jj >> 5;
        } else if (j < 8192){
            int jj = j - 4096;
            in = w1; out = w1_t; K = 1024; N = 4096; bx = jj & 127; by = jj >> 7;
        } else {
            int jj = j - 8192;
            in = w2; out = w2_t; K = 4096; N = 1024; bx = jj & 31; by = jj >> 5;
        }
        int tx = tid & 31, ty = tid >> 5;
        #pragma unroll
        for (int r = 0; r < 4; ++r)
            t[ty + r*8][tx] = f2bf(in[(size_t)(by*32 + ty + r*8) * N + bx*32 + tx]);
        __syncthreads();
        #pragma unroll
        for (int r = 0; r < 4; ++r)
            out[(size_t)(bx*32 + ty + r*8) * K + by*32 + tx] = t[tx][ty + r*8];
    }
}

// ---------------- LayerNorm (row = 1024), f32 in -> bf16 out ----------------
__global__ __launch_bounds__(256) void ln_kernel(const float* __restrict__ xin,
                                                 const float* __restrict__ g,
                                                 const float* __restrict__ bia,
                                                 ushort_t* __restrict__ out){
    int row = blockIdx.x;
    int tid = threadIdx.x;
    const float* x = xin + (size_t)row * EMB;
    float4 f = *(const float4*)(x + tid*4);
    float v[4] = {f.x, f.y, f.z, f.w};
    float s = v[0]+v[1]+v[2]+v[3];
    float q = v[0]*v[0]+v[1]*v[1]+v[2]*v[2]+v[3]*v[3];
    #pragma unroll
    for (int o = 32; o > 0; o >>= 1){ s += __shfl_down(s, o); q += __shfl_down(q, o); }
    __shared__ float ss[4], qq[4];
    __shared__ float mu_s, sc_s;
    int wave = tid >> 6, lane = tid & 63;
    if (lane == 0){ ss[wave] = s; qq[wave] = q; }
    __syncthreads();
    if (tid == 0){
        float S = ss[0]+ss[1]+ss[2]+ss[3];
        float Q = qq[0]+qq[1]+qq[2]+qq[3];
        float mu = S * (1.0f/EMB);
        float var = Q * (1.0f/EMB) - mu*mu;
        mu_s = mu; sc_s = rsqrtf(var + 1e-5f);
    }
    __syncthreads();
    float mu = mu_s, sc = sc_s;
    float4 gu = *(const float4*)(g + tid*4);
    float4 bu = *(const float4*)(bia + tid*4);
    ushort4 o4;
    o4.x = f2bf((v[0]-mu)*sc*gu.x + bu.x);
    o4.y = f2bf((v[1]-mu)*sc*gu.y + bu.y);
    o4.z = f2bf((v[2]-mu)*sc*gu.z + bu.z);
    o4.w = f2bf((v[3]-mu)*sc*gu.w + bu.w);
    *(ushort4*)(out + (size_t)row*EMB + tid*4) = o4;
}

// ---------------- GEMM: 128x128 tile, EIGHT waves, 32x32x16 MFMA, XOR-swizzled LDS ----------
// r0's exact schedule/tiling/swizzle (single-buffer, 2 syncthreads/K-tile, staged bytes
// unchanged) -- the ONLY change is 8 waves/block instead of 4. Empirical law from rounds
// 0-5: staging rate ~= 0.95 TB/s per resident wave per CU; resident waves were the binding
// resource in every config. 8 waves at ~64-80 VGPR (acc shrinks to 32 regs/wave) doubles
// waves-per-block while LDS stays 32KB -> target 24 waves/CU (launch_bounds cap 85 VGPR).
// Per-wave: stages 16 A-rows + 16 B-rows (4 gload16), computes a 32x64 output (1m x 2n
// 32x32 frags, 8 MFMA/K-tile). LDS chunk invariant unchanged: physical chunk c of row r
// holds global chunk c^(r&7); reads at rows ?*32+l31 use sx = lane&7 = r&7.
// MODE 0: plain -> bf16 | 1: +bias+resid -> f32 | 2: +bias+GELU -> bf16 | 3: +bias+resid -> f32
template<int MODE>
__global__ __launch_bounds__(512, 6) void gemm_kernel(const ushort_t* __restrict__ A,
                                                      const ushort_t* __restrict__ Bt,
                                                      const float* __restrict__ bias,
                                                      const float* __restrict__ resid,
                                                      void* __restrict__ out,
                                                      int M, int N, int K){
    __shared__ ushort_t As[128*64];   // 16KB
    __shared__ ushort_t Bs[128*64];   // 16KB
    int tid = threadIdx.x;
    int lane = tid & 63, wave = tid >> 6;   // 8 waves
    int l31 = lane & 31, half = lane >> 5;
    int wm = wave >> 1, wn = wave & 1;      // 4m x 2n wave grid; per-wave out 32x64
    int bid = blockIdx.x;
    int m0 = (bid & 63) * 128, n0 = (bid >> 6) * 128;

    f32x16 acc[2];
    #pragma unroll
    for (int j=0;j<2;j++)
        #pragma unroll
        for (int r=0;r<16;r++) acc[j][r] = 0.f;

    int lr  = lane >> 3;        // row within 8-row group
    int lch = lane & 7;         // destination LDS chunk
    const ushort_t* gA = A  + (size_t)(m0 + wave*16 + lr)*K + (lch ^ lr)*8;
    const ushort_t* gB = Bt + (size_t)(n0 + wave*16 + lr)*K + (lch ^ lr)*8;
    ushort_t* lA = &As[(wave*16)*64];
    ushort_t* lB = &Bs[(wave*16)*64];
    int sx = lane & 7;          // fragment-read swizzle (row&7 == lane&7)

    for (int k0 = 0; k0 < K; k0 += 64){
        gload16(gA + k0, lA);
        gload16(gA + (size_t)8*K + k0, lA + 8*64);
        gload16(gB + k0, lB);
        gload16(gB + (size_t)8*K + k0, lB + 8*64);
        __syncthreads();
        #pragma unroll
        for (int s = 0; s < 4; ++s){
            int ch = ((s<<1) | half) ^ sx;
            bf16x8 af = *(const bf16x8*)&As[(wm*32 + l31)*64 + ch*8];
            bf16x8 bfr[2];
            #pragma unroll
            for (int j=0;j<2;j++) bfr[j] = *(const bf16x8*)&Bs[(wn*64 + j*32 + l31)*64 + ch*8];
            #pragma unroll
            for (int j=0;j<2;j++)
                acc[j] = __builtin_amdgcn_mfma_f32_32x32x16_bf16(af, bfr[j], acc[j], 0,0,0);
        }
        __syncthreads();
    }

    // C/D layout (32x32): col = lane&31, row = (reg&3) + 8*(reg>>2) + 4*(lane>>5)
    int rowoff = 4*half;
    #pragma unroll
    for (int j=0;j<2;j++){
        int n = n0 + wn*64 + j*32 + l31;
        #pragma unroll
        for (int reg=0; reg<16; ++reg){
            int m = m0 + wm*32 + (reg&3) + 8*(reg>>2) + rowoff;
            float v = acc[j][reg];
            size_t idx = (size_t)m*N + n;
            if (MODE == 0){
                ((ushort_t*)out)[idx] = f2bf(v);
            } else if (MODE == 1){
                v += bias[n] + resid[idx];
                ((float*)out)[idx] = v;
            } else if (MODE == 2){
                v += bias[n];
                ((ushort_t*)out)[idx] = f2bf(gelu_f(v));
            } else {
                v += bias[n] + resid[idx];
                ((float*)out)[idx] = v;
            }
        }
    }
}

// ---------------- Flash attention (causal), S^T formulation ----------------
__global__ __launch_bounds__(256) void attn_kernel(const ushort_t* __restrict__ qkv,
                                                   ushort_t* __restrict__ attn_out){
    __shared__ ushort_t Qs[128*64];    // [q][d], gload chunk-swizzled
    __shared__ ushort_t Ks[64*64];     // [kv][d], gload chunk-swizzled
    __shared__ ushort_t Vts[64][72];   // V^T [d][kv], write-swizzled
    __shared__ ushort_t Ps[128*64];    // P [q][kv], XOR-slotted

    int tid = threadIdx.x;
    int lane = tid & 63, wave = tid >> 6;
    int quad = lane >> 4, l15 = lane & 15;
    int pair = blockIdx.x;         // 0..3
    int bh = blockIdx.y;           // 0..127
    int b = bh >> 4, h = bh & 15;
    size_t tb = (size_t)b * SEQ;

    int lr = lane >> 3, lch = lane & 7;   // gload lane decomposition
    int tr = tid >> 3;                    // V staging: rows 0..31
    int tc = (tid & 7) * 8;
    int sw_w = tid & 7;
    int sx = l15 & 7;                     // fragment-read chunk swizzle

    for (int t = 0; t < 2; ++t){
        int qi = t ? (7 - pair) : pair;

        {
            const ushort_t* gq = qkv + (size_t)(tb + qi*128 + wave*32 + lr)*3072 + h*64 + (lch^lr)*8;
            ushort_t* lq = &Qs[(wave*32)*64];
            #pragma unroll
            for (int p = 0; p < 4; ++p)
                gload16(gq + (size_t)(p*8)*3072, lq + p*8*64);
        }

        f32x4 o_acc[4][2];
        #pragma unroll
        for (int i=0;i<4;i++)
            #pragma unroll
            for (int j=0;j<2;j++) o_acc[i][j] = (f32x4){0.f,0.f,0.f,0.f};
        float m_st[2] = {-1e30f, -1e30f};
        float l_st[2] = {0.f, 0.f};

        int nj = 2*qi + 2;
        for (int j = 0; j < nj; ++j){
            {
                const ushort_t* gk = qkv + (size_t)(tb + j*64 + wave*16 + lr)*3072 + 1024 + h*64 + (lch^lr)*8;
                ushort_t* lk = &Ks[(wave*16)*64];
                gload16(gk, lk);
                gload16(gk + (size_t)8*3072, lk + 8*64);
            }
            #pragma unroll
            for (int p = 0; p < 2; ++p){
                int r = tr + p*32;
                bf16x8 vv = *(const bf16x8*)(qkv + (size_t)(tb + j*64 + r)*3072 + 2048 + h*64 + tc);
                int kcol = r ^ (sw_w << 3);
                #pragma unroll
                for (int c = 0; c < 8; ++c) Vts[tc + c][kcol] = (ushort_t)vv[c];
            }
            __syncthreads();

            // S^T[kv 64][q 32/wave] = K·Q^T
            f32x4 st[4][2];
            #pragma unroll
            for (int mt=0;mt<4;mt++)
                #pragma unroll
                for (int nt=0;nt<2;nt++) st[mt][nt] = (f32x4){0.f,0.f,0.f,0.f};
            #pragma unroll
            for (int kf = 0; kf < 2; ++kf){
                int ch = (kf*4 + quad) ^ sx;
                bf16x8 ak[4], bq[2];
                #pragma unroll
                for (int mt=0;mt<4;mt++) ak[mt] = *(const bf16x8*)&Ks[(mt*16 + l15)*64 + ch*8];
                #pragma unroll
                for (int nt=0;nt<2;nt++) bq[nt] = *(const bf16x8*)&Qs[(wave*32 + nt*16 + l15)*64 + ch*8];
                #pragma unroll
                for (int mt=0;mt<4;mt++)
                    #pragma unroll
                    for (int nt=0;nt<2;nt++)
                        st[mt][nt] = __builtin_amdgcn_mfma_f32_16x16x32_bf16(ak[mt], bq[nt], st[mt][nt], 0,0,0);
            }

            bool need_mask = (j >= 2*qi);
            #pragma unroll
            for (int mt=0;mt<4;mt++)
                #pragma unroll
                for (int nt=0;nt<2;nt++)
                    #pragma unroll
                    for (int r=0;r<4;r++){
                        float s = st[mt][nt][r] * 0.125f;
                        if (need_mask){
                            int kg = j*64 + mt*16 + quad*4 + r;
                            int qg = qi*128 + wave*32 + nt*16 + l15;
                            if (kg > qg) s = -1e30f;
                        }
                        st[mt][nt][r] = s;
                    }

            #pragma unroll
            for (int nt = 0; nt < 2; ++nt){
                float mx = st[0][nt][0];
                #pragma unroll
                for (int mt=0;mt<4;mt++)
                    #pragma unroll
                    for (int r=0;r<4;r++) mx = fmaxf(mx, st[mt][nt][r]);
                mx = fmaxf(mx, __shfl_xor(mx, 16));
                mx = fmaxf(mx, __shfl_xor(mx, 32));
                float mnew = fmaxf(m_st[nt], mx);
                float al = __expf(m_st[nt] - mnew);
                float ps = 0.f;
                #pragma unroll
                for (int mt=0;mt<4;mt++)
                    #pragma unroll
                    for (int r=0;r<4;r++){
                        float p = __expf(st[mt][nt][r] - mnew);
                        st[mt][nt][r] = p;
                        ps += p;
                    }
                ps += __shfl_xor(ps, 16);
                ps += __shfl_xor(ps, 32);
                l_st[nt] = l_st[nt]*al + ps;
                m_st[nt] = mnew;
                #pragma unroll
                for (int mtd=0;mtd<4;mtd++)
                    #pragma unroll
                    for (int r=0;r<4;r++) o_acc[mtd][nt][r] *= al;
                #pragma unroll
                for (int mt=0;mt<4;mt++){
                    int slot = (mt*2 + (quad>>1)) ^ sx;
                    ushort4 pk;
                    pk.x = f2bf(st[mt][nt][0]); pk.y = f2bf(st[mt][nt][1]);
                    pk.z = f2bf(st[mt][nt][2]); pk.w = f2bf(st[mt][nt][3]);
                    *(ushort4*)&Ps[(wave*32 + nt*16 + l15)*64 + slot*8 + (quad&1)*4] = pk;
                }
            }

            // O^T[d 64][q 32/wave] += V^T·P^T
            #pragma unroll
            for (int kf = 0; kf < 2; ++kf){
                bf16x8 av[4], bp[2];
                #pragma unroll
                for (int mtd=0;mtd<4;mtd++){
                    int d = mtd*16 + l15;
                    int col = (kf*32 + quad*8) ^ (((d >> 3) & 7) << 3);
                    av[mtd] = *(const bf16x8*)&Vts[d][col];
                }
                #pragma unroll
                for (int nt=0;nt<2;nt++){
                    int ch = (kf*4 + quad) ^ sx;
                    bp[nt] = *(const bf16x8*)&Ps[(wave*32 + nt*16 + l15)*64 + ch*8];
                }
                #pragma unroll
                for (int mtd=0;mtd<4;mtd++)
                    #pragma unroll
                    for (int nt=0;nt<2;nt++)
                        o_acc[mtd][nt] = __builtin_amdgcn_mfma_f32_16x16x32_bf16(av[mtd], bp[nt], o_acc[mtd][nt], 0,0,0);
            }
            __syncthreads();
        }

        #pragma unroll
        for (int nt = 0; nt < 2; ++nt){
            float inv = 1.0f / l_st[nt];
            size_t tok = tb + qi*128 + wave*32 + nt*16 + l15;
            #pragma unroll
            for (int mtd = 0; mtd < 4; ++mtd){
                ushort4 ok;
                ok.x = f2bf(o_acc[mtd][nt][0]*inv); ok.y = f2bf(o_acc[mtd][nt][1]*inv);
                ok.z = f2bf(o_acc[mtd][nt][2]*inv); ok.w = f2bf(o_acc[mtd][nt][3]*inv);
                *(ushort4*)(attn_out + tok*EMB + h*64 + mtd*16 + quad*4) = ok;
            }
        }
    }
}

extern "C" void kernel_launch(void* const* d_in, const int* in_sizes, int n_in,
                              void* d_out, int out_size, void* d_ws, size_t ws_size,
                              hipStream_t stream){
    const float* x      = (const float*)d_in[0];
    const float* ln1_g  = (const float*)d_in[1];
    const float* ln1_b  = (const float*)d_in[2];
    const float* wq     = (const float*)d_in[3];
    const float* wk     = (const float*)d_in[4];
    const float* wv     = (const float*)d_in[5];
    const float* w_proj = (const float*)d_in[6];
    const float* b_proj = (const float*)d_in[7];
    const float* ln2_g  = (const float*)d_in[8];
    const float* ln2_b  = (const float*)d_in[9];
    const float* w1     = (const float*)d_in[10];
    const float* b1     = (const float*)d_in[11];
    const float* w2     = (const float*)d_in[12];
    const float* b2     = (const float*)d_in[13];
    float* outp = (float*)d_out;

    char* ws = (char*)d_ws;
    size_t off = 0;
    auto alloc = [&](size_t bytes)->char*{ char* p = ws + off; off += (bytes + 255) & ~255ULL; return p; };
    ushort_t* wqkv_t = (ushort_t*)alloc((size_t)3072*1024*2);
    ushort_t* wproj_t= (ushort_t*)alloc((size_t)1024*1024*2);
    ushort_t* w1_t   = (ushort_t*)alloc((size_t)4096*1024*2);
    ushort_t* w2_t   = (ushort_t*)alloc((size_t)1024*4096*2);
    ushort_t* qkv    = (ushort_t*)alloc((size_t)ROWS*3072*2);
    ushort_t* hbuf   = (ushort_t*)alloc((size_t)ROWS*1024*2);
    float*    out32  = (float*)  alloc((size_t)ROWS*1024*4);
    ushort_t* mid    = (ushort_t*)alloc((size_t)ROWS*4096*2);
    ushort_t* h1 = hbuf;
    ushort_t* attn = hbuf;   // h1 dead after qkv GEMM
    ushort_t* h2 = qkv;      // qkv dead after attention

    dim3 blk(256);
    dim3 gblk(512);
    // blocks: 8192 LN1 rows + 3072 (wq/wk/wv) + 1024 (wproj) + 4096 (w1) + 4096 (w2)
    prep_kernel<<<dim3(20480), blk, 0, stream>>>(x, ln1_g, ln1_b, h1,
                                                 wq, wk, wv, w_proj, w1, w2,
                                                 wqkv_t, wproj_t, w1_t, w2_t);
    // same grids as r0 (tiles unchanged), blocks now 512 threads / 8 waves:
    gemm_kernel<0><<<dim3(64*(3072/128)), gblk, 0, stream>>>(h1, wqkv_t, nullptr, nullptr, qkv, ROWS, 3072, 1024);
    attn_kernel<<<dim3(4,128), blk, 0, stream>>>(qkv, attn);
    gemm_kernel<1><<<dim3(64*(1024/128)), gblk, 0, stream>>>(attn, wproj_t, b_proj, x, out32, ROWS, 1024, 1024);
    ln_kernel<<<ROWS, blk, 0, stream>>>(out32, ln2_g, ln2_b, h2);
    gemm_kernel<2><<<dim3(64*(4096/128)), gblk, 0, stream>>>(h2, w1_t, b1, nullptr, mid, ROWS, 4096, 1024);
    gemm_kernel<3><<<dim3(64*(1024/128)), gblk, 0, stream>>>(mid, w2_t, b2, out32, outp, ROWS, 1024, 4096);
}

// Round 7
// 458.303 us; speedup vs baseline: 1.3762x; 1.0690x over previous
//
#include <hip/hip_runtime.h>
#include <hip/hip_bf16.h>

#define EMB 1024
#define NH 16
#define HD 64
#define BATCH 8
#define SEQ 1024
#define ROWS (BATCH*SEQ)   // 8192

typedef unsigned short ushort_t;
typedef __attribute__((ext_vector_type(8))) short bf16x8;
typedef __attribute__((ext_vector_type(4))) float f32x4;
typedef __attribute__((ext_vector_type(16))) float f32x16;

__device__ __forceinline__ float bf2f(ushort_t u){
    union { unsigned int i; float f; } v; v.i = ((unsigned int)u) << 16; return v.f;
}
__device__ __forceinline__ ushort_t f2bf(float f){
    unsigned int u = __float_as_uint(f);
    unsigned int r = (u + 0x7FFFu + ((u >> 16) & 1u)) >> 16;
    return (ushort_t)r;
}
__device__ __forceinline__ void gload16(const ushort_t* g, ushort_t* l){
    __builtin_amdgcn_global_load_lds(
        (const __attribute__((address_space(1))) void*)g,
        (__attribute__((address_space(3))) void*)l,
        16, 0, 0);
}
// exact-erf GELU via A&S 7.1.26 (|err| < 1.5e-7)
__device__ __forceinline__ float gelu_f(float v){
    float x = fabsf(v) * 0.70710678118654752f;
    float t = __builtin_amdgcn_rcpf(1.0f + 0.3275911f * x);
    float poly = t*(0.254829592f + t*(-0.284496736f + t*(1.421413741f + t*(-1.453152027f + t*1.061405429f))));
    float erfa = 1.0f - poly * __expf(-x*x);
    float erfv = (v >= 0.f) ? erfa : -erfa;
    return 0.5f * v * (1.0f + erfv);
}

// ---------------- fused prep: LN1 (blocks 0..8191) + all 6 weight transposes ----------------
__global__ __launch_bounds__(256) void prep_kernel(const float* __restrict__ x,
                                                   const float* __restrict__ ln1_g,
                                                   const float* __restrict__ ln1_b,
                                                   ushort_t* __restrict__ h1,
                                                   const float* __restrict__ wq,
                                                   const float* __restrict__ wk,
                                                   const float* __restrict__ wv,
                                                   const float* __restrict__ w_proj,
                                                   const float* __restrict__ w1,
                                                   const float* __restrict__ w2,
                                                   ushort_t* __restrict__ wqkv_t,
                                                   ushort_t* __restrict__ wproj_t,
                                                   ushort_t* __restrict__ w1_t,
                                                   ushort_t* __restrict__ w2_t){
    int bid = blockIdx.x;
    int tid = threadIdx.x;
    if (bid < ROWS){
        __shared__ float ss[4], qq[4];
        __shared__ float mu_s, sc_s;
        const float* xr = x + (size_t)bid * EMB;
        float4 f = *(const float4*)(xr + tid*4);
        float v[4] = {f.x, f.y, f.z, f.w};
        float s = v[0]+v[1]+v[2]+v[3];
        float q = v[0]*v[0]+v[1]*v[1]+v[2]*v[2]+v[3]*v[3];
        #pragma unroll
        for (int o = 32; o > 0; o >>= 1){ s += __shfl_down(s, o); q += __shfl_down(q, o); }
        int wave = tid >> 6, lane = tid & 63;
        if (lane == 0){ ss[wave] = s; qq[wave] = q; }
        __syncthreads();
        if (tid == 0){
            float S = ss[0]+ss[1]+ss[2]+ss[3];
            float Q = qq[0]+qq[1]+qq[2]+qq[3];
            float mu = S * (1.0f/EMB);
            float var = Q * (1.0f/EMB) - mu*mu;
            mu_s = mu; sc_s = rsqrtf(var + 1e-5f);
        }
        __syncthreads();
        float mu = mu_s, sc = sc_s;
        float4 gu = *(const float4*)(ln1_g + tid*4);
        float4 bu = *(const float4*)(ln1_b + tid*4);
        ushort4 o4;
        o4.x = f2bf((v[0]-mu)*sc*gu.x + bu.x);
        o4.y = f2bf((v[1]-mu)*sc*gu.y + bu.y);
        o4.z = f2bf((v[2]-mu)*sc*gu.z + bu.z);
        o4.w = f2bf((v[3]-mu)*sc*gu.w + bu.w);
        *(ushort4*)(h1 + (size_t)bid*EMB + tid*4) = o4;
    } else {
        __shared__ ushort_t t[32][33];
        int j = bid - ROWS;
        const float* in; ushort_t* out; int K, N, bx, by;
        if (j < 3072){
            int which = j >> 10, jj = j & 1023;
            in = (which == 0) ? wq : (which == 1) ? wk : wv;
            out = wqkv_t + (size_t)which * 1024 * 1024;
            K = 1024; N = 1024; bx = jj & 31; by = jj >> 5;
        } else if (j < 4096){
            int jj = j - 3072;
            in = w_proj; out = wproj_t; K = 1024; N = 1024; bx = jj & 31; by = jj >> 5;
        } else if (j < 8192){
            int jj = j - 4096;
            in = w1; out = w1_t; K = 1024; N = 4096; bx = jj & 127; by = jj >> 7;
        } else {
            int jj = j - 8192;
            in = w2; out = w2_t; K = 4096; N = 1024; bx = jj & 31; by = jj >> 5;
        }
        int tx = tid & 31, ty = tid >> 5;
        #pragma unroll
        for (int r = 0; r < 4; ++r)
            t[ty + r*8][tx] = f2bf(in[(size_t)(by*32 + ty + r*8) * N + bx*32 + tx]);
        __syncthreads();
        #pragma unroll
        for (int r = 0; r < 4; ++r)
            out[(size_t)(bx*32 + ty + r*8) * K + by*32 + tx] = t[tx][ty + r*8];
    }
}

// ---------------- LayerNorm (row = 1024), f32 in -> bf16 out ----------------
__global__ __launch_bounds__(256) void ln_kernel(const float* __restrict__ xin,
                                                 const float* __restrict__ g,
                                                 const float* __restrict__ bia,
                                                 ushort_t* __restrict__ out){
    int row = blockIdx.x;
    int tid = threadIdx.x;
    const float* x = xin + (size_t)row * EMB;
    float4 f = *(const float4*)(x + tid*4);
    float v[4] = {f.x, f.y, f.z, f.w};
    float s = v[0]+v[1]+v[2]+v[3];
    float q = v[0]*v[0]+v[1]*v[1]+v[2]*v[2]+v[3]*v[3];
    #pragma unroll
    for (int o = 32; o > 0; o >>= 1){ s += __shfl_down(s, o); q += __shfl_down(q, o); }
    __shared__ float ss[4], qq[4];
    __shared__ float mu_s, sc_s;
    int wave = tid >> 6, lane = tid & 63;
    if (lane == 0){ ss[wave] = s; qq[wave] = q; }
    __syncthreads();
    if (tid == 0){
        float S = ss[0]+ss[1]+ss[2]+ss[3];
        float Q = qq[0]+qq[1]+qq[2]+qq[3];
        float mu = S * (1.0f/EMB);
        float var = Q * (1.0f/EMB) - mu*mu;
        mu_s = mu; sc_s = rsqrtf(var + 1e-5f);
    }
    __syncthreads();
    float mu = mu_s, sc = sc_s;
    float4 gu = *(const float4*)(g + tid*4);
    float4 bu = *(const float4*)(bia + tid*4);
    ushort4 o4;
    o4.x = f2bf((v[0]-mu)*sc*gu.x + bu.x);
    o4.y = f2bf((v[1]-mu)*sc*gu.y + bu.y);
    o4.z = f2bf((v[2]-mu)*sc*gu.z + bu.z);
    o4.w = f2bf((v[3]-mu)*sc*gu.w + bu.w);
    *(ushort4*)(out + (size_t)row*EMB + tid*4) = o4;
}

// ---------------- GEMM: 128x128 tile, 8 waves, 32x32x16 MFMA, XOR-swizzled LDS, ------------
// ---------------- DOUBLE-buffered with issue-first COUNTED vmcnt ----------------
// r6's exact staging geometry/swizzle/fragments/epilogue; only the loop schedule changes.
// Per tile: issue tile t+1's 4 gload16 FIRST, then s_waitcnt vmcnt(4) -- waits only for
// tile t's 4 loads, which were issued a full tile period earlier (wait ~ 0 in steady
// state); t+1's loads stay in flight THROUGH the compute phase (F ~ 4-8 vs r6's ~2).
// This is r4's bug fixed: r4 waited vmcnt(0) for the *next* tile's loads (zero lead).
// 2 barriers/tile (same as r6). Buffer index is compile-time via 2x-unrolled loop.
// WAR: stage(t+1) writes buf[t^1], last read at tile t-1, protected by t-1's end barrier.
// RAW: per-wave FIFO vmcnt + barrier => all waves' tile-t loads landed before compute.
// ds_reads are consumed by MFMAs before the end barrier (compiler lgkmcnt) -- no overrun.
// MODE 0: plain -> bf16 | 1: +bias+resid -> f32 | 2: +bias+GELU -> bf16 | 3: +bias+resid -> f32
template<int MODE>
__global__ __launch_bounds__(512, 4) void gemm_kernel(const ushort_t* __restrict__ A,
                                                      const ushort_t* __restrict__ Bt,
                                                      const float* __restrict__ bias,
                                                      const float* __restrict__ resid,
                                                      void* __restrict__ out,
                                                      int M, int N, int K){
    __shared__ ushort_t As[2][128*64];   // 2 x 16KB
    __shared__ ushort_t Bs[2][128*64];   // 2 x 16KB  -> 64KB total, 2 blocks/CU
    int tid = threadIdx.x;
    int lane = tid & 63, wave = tid >> 6;   // 8 waves
    int l31 = lane & 31, half = lane >> 5;
    int wm = wave >> 1, wn = wave & 1;      // 4m x 2n wave grid; per-wave out 32x64
    int bid = blockIdx.x;
    int m0 = (bid & 63) * 128, n0 = (bid >> 6) * 128;

    f32x16 acc[2];
    #pragma unroll
    for (int j=0;j<2;j++)
        #pragma unroll
        for (int r=0;r<16;r++) acc[j][r] = 0.f;

    int lr  = lane >> 3;        // row within 8-row group
    int lch = lane & 7;         // destination LDS chunk
    const ushort_t* gA = A  + (size_t)(m0 + wave*16 + lr)*K + (lch ^ lr)*8;
    const ushort_t* gB = Bt + (size_t)(n0 + wave*16 + lr)*K + (lch ^ lr)*8;
    int lo = (wave*16)*64;      // this wave's staging offset within a buffer
    int sx = lane & 7;          // fragment-read swizzle (row&7 == lane&7)
    int NT = K >> 6;            // 16 or 64 -- always even

// one K-tile with compile-time buffer index B, runtime tile index T
#define GTILE(B, T)                                                                       \
    {                                                                                     \
        if ((T) + 1 < NT){                                                                \
            int nk0 = ((T) + 1) << 6;                                                     \
            gload16(gA + nk0,               &As[(B)^1][lo]);                              \
            gload16(gA + (size_t)8*K + nk0, &As[(B)^1][lo + 8*64]);                       \
            gload16(gB + nk0,               &Bs[(B)^1][lo]);                              \
            gload16(gB + (size_t)8*K + nk0, &Bs[(B)^1][lo + 8*64]);                       \
            asm volatile("s_waitcnt vmcnt(4)" ::: "memory");                              \
        } else {                                                                          \
            asm volatile("s_waitcnt vmcnt(0)" ::: "memory");                              \
        }                                                                                 \
        __builtin_amdgcn_s_barrier();                                                     \
        asm volatile("" ::: "memory");                                                    \
        _Pragma("unroll")                                                                 \
        for (int s = 0; s < 4; ++s){                                                      \
            int ch = ((s<<1) | half) ^ sx;                                                \
            bf16x8 af  = *(const bf16x8*)&As[B][(wm*32 + l31)*64 + ch*8];                 \
            bf16x8 bf0 = *(const bf16x8*)&Bs[B][(wn*64 + l31)*64 + ch*8];                 \
            bf16x8 bf1 = *(const bf16x8*)&Bs[B][(wn*64 + 32 + l31)*64 + ch*8];            \
            acc[0] = __builtin_amdgcn_mfma_f32_32x32x16_bf16(af, bf0, acc[0], 0,0,0);     \
            acc[1] = __builtin_amdgcn_mfma_f32_32x32x16_bf16(af, bf1, acc[1], 0,0,0);     \
        }                                                                                 \
        asm volatile("" ::: "memory");                                                    \
        __builtin_amdgcn_s_barrier();                                                     \
        asm volatile("" ::: "memory");                                                    \
    }

    // prologue: stage tile 0 into buf 0 (no wait here; GTILE(0,0) waits vmcnt(4))
    gload16(gA,               &As[0][lo]);
    gload16(gA + (size_t)8*K, &As[0][lo + 8*64]);
    gload16(gB,               &Bs[0][lo]);
    gload16(gB + (size_t)8*K, &Bs[0][lo + 8*64]);

    for (int t = 0; t < NT; t += 2){
        GTILE(0, t)
        GTILE(1, t+1)
    }
#undef GTILE

    // C/D layout (32x32): col = lane&31, row = (reg&3) + 8*(reg>>2) + 4*(lane>>5)
    int rowoff = 4*half;
    #pragma unroll
    for (int j=0;j<2;j++){
        int n = n0 + wn*64 + j*32 + l31;
        #pragma unroll
        for (int reg=0; reg<16; ++reg){
            int m = m0 + wm*32 + (reg&3) + 8*(reg>>2) + rowoff;
            float v = acc[j][reg];
            size_t idx = (size_t)m*N + n;
            if (MODE == 0){
                ((ushort_t*)out)[idx] = f2bf(v);
            } else if (MODE == 1){
                v += bias[n] + resid[idx];
                ((float*)out)[idx] = v;
            } else if (MODE == 2){
                v += bias[n];
                ((ushort_t*)out)[idx] = f2bf(gelu_f(v));
            } else {
                v += bias[n] + resid[idx];
                ((float*)out)[idx] = v;
            }
        }
    }
}

// ---------------- Flash attention (causal), S^T formulation ----------------
__global__ __launch_bounds__(256) void attn_kernel(const ushort_t* __restrict__ qkv,
                                                   ushort_t* __restrict__ attn_out){
    __shared__ ushort_t Qs[128*64];    // [q][d], gload chunk-swizzled
    __shared__ ushort_t Ks[64*64];     // [kv][d], gload chunk-swizzled
    __shared__ ushort_t Vts[64][72];   // V^T [d][kv], write-swizzled
    __shared__ ushort_t Ps[128*64];    // P [q][kv], XOR-slotted

    int tid = threadIdx.x;
    int lane = tid & 63, wave = tid >> 6;
    int quad = lane >> 4, l15 = lane & 15;
    int pair = blockIdx.x;         // 0..3
    int bh = blockIdx.y;           // 0..127
    int b = bh >> 4, h = bh & 15;
    size_t tb = (size_t)b * SEQ;

    int lr = lane >> 3, lch = lane & 7;   // gload lane decomposition
    int tr = tid >> 3;                    // V staging: rows 0..31
    int tc = (tid & 7) * 8;
    int sw_w = tid & 7;
    int sx = l15 & 7;                     // fragment-read chunk swizzle

    for (int t = 0; t < 2; ++t){
        int qi = t ? (7 - pair) : pair;

        {
            const ushort_t* gq = qkv + (size_t)(tb + qi*128 + wave*32 + lr)*3072 + h*64 + (lch^lr)*8;
            ushort_t* lq = &Qs[(wave*32)*64];
            #pragma unroll
            for (int p = 0; p < 4; ++p)
                gload16(gq + (size_t)(p*8)*3072, lq + p*8*64);
        }

        f32x4 o_acc[4][2];
        #pragma unroll
        for (int i=0;i<4;i++)
            #pragma unroll
            for (int j=0;j<2;j++) o_acc[i][j] = (f32x4){0.f,0.f,0.f,0.f};
        float m_st[2] = {-1e30f, -1e30f};
        float l_st[2] = {0.f, 0.f};

        int nj = 2*qi + 2;
        for (int j = 0; j < nj; ++j){
            {
                const ushort_t* gk = qkv + (size_t)(tb + j*64 + wave*16 + lr)*3072 + 1024 + h*64 + (lch^lr)*8;
                ushort_t* lk = &Ks[(wave*16)*64];
                gload16(gk, lk);
                gload16(gk + (size_t)8*3072, lk + 8*64);
            }
            #pragma unroll
            for (int p = 0; p < 2; ++p){
                int r = tr + p*32;
                bf16x8 vv = *(const bf16x8*)(qkv + (size_t)(tb + j*64 + r)*3072 + 2048 + h*64 + tc);
                int kcol = r ^ (sw_w << 3);
                #pragma unroll
                for (int c = 0; c < 8; ++c) Vts[tc + c][kcol] = (ushort_t)vv[c];
            }
            __syncthreads();

            // S^T[kv 64][q 32/wave] = K·Q^T
            f32x4 st[4][2];
            #pragma unroll
            for (int mt=0;mt<4;mt++)
                #pragma unroll
                for (int nt=0;nt<2;nt++) st[mt][nt] = (f32x4){0.f,0.f,0.f,0.f};
            #pragma unroll
            for (int kf = 0; kf < 2; ++kf){
                int ch = (kf*4 + quad) ^ sx;
                bf16x8 ak[4], bq[2];
                #pragma unroll
                for (int mt=0;mt<4;mt++) ak[mt] = *(const bf16x8*)&Ks[(mt*16 + l15)*64 + ch*8];
                #pragma unroll
                for (int nt=0;nt<2;nt++) bq[nt] = *(const bf16x8*)&Qs[(wave*32 + nt*16 + l15)*64 + ch*8];
                #pragma unroll
                for (int mt=0;mt<4;mt++)
                    #pragma unroll
                    for (int nt=0;nt<2;nt++)
                        st[mt][nt] = __builtin_amdgcn_mfma_f32_16x16x32_bf16(ak[mt], bq[nt], st[mt][nt], 0,0,0);
            }

            bool need_mask = (j >= 2*qi);
            #pragma unroll
            for (int mt=0;mt<4;mt++)
                #pragma unroll
                for (int nt=0;nt<2;nt++)
                    #pragma unroll
                    for (int r=0;r<4;r++){
                        float s = st[mt][nt][r] * 0.125f;
                        if (need_mask){
                            int kg = j*64 + mt*16 + quad*4 + r;
                            int qg = qi*128 + wave*32 + nt*16 + l15;
                            if (kg > qg) s = -1e30f;
                        }
                        st[mt][nt][r] = s;
                    }

            #pragma unroll
            for (int nt = 0; nt < 2; ++nt){
                float mx = st[0][nt][0];
                #pragma unroll
                for (int mt=0;mt<4;mt++)
                    #pragma unroll
                    for (int r=0;r<4;r++) mx = fmaxf(mx, st[mt][nt][r]);
                mx = fmaxf(mx, __shfl_xor(mx, 16));
                mx = fmaxf(mx, __shfl_xor(mx, 32));
                float mnew = fmaxf(m_st[nt], mx);
                float al = __expf(m_st[nt] - mnew);
                float ps = 0.f;
                #pragma unroll
                for (int mt=0;mt<4;mt++)
                    #pragma unroll
                    for (int r=0;r<4;r++){
                        float p = __expf(st[mt][nt][r] - mnew);
                        st[mt][nt][r] = p;
                        ps += p;
                    }
                ps += __shfl_xor(ps, 16);
                ps += __shfl_xor(ps, 32);
                l_st[nt] = l_st[nt]*al + ps;
                m_st[nt] = mnew;
                #pragma unroll
                for (int mtd=0;mtd<4;mtd++)
                    #pragma unroll
                    for (int r=0;r<4;r++) o_acc[mtd][nt][r] *= al;
                #pragma unroll
                for (int mt=0;mt<4;mt++){
                    int slot = (mt*2 + (quad>>1)) ^ sx;
                    ushort4 pk;
                    pk.x = f2bf(st[mt][nt][0]); pk.y = f2bf(st[mt][nt][1]);
                    pk.z = f2bf(st[mt][nt][2]); pk.w = f2bf(st[mt][nt][3]);
                    *(ushort4*)&Ps[(wave*32 + nt*16 + l15)*64 + slot*8 + (quad&1)*4] = pk;
                }
            }

            // O^T[d 64][q 32/wave] += V^T·P^T
            #pragma unroll
            for (int kf = 0; kf < 2; ++kf){
                bf16x8 av[4], bp[2];
                #pragma unroll
                for (int mtd=0;mtd<4;mtd++){
                    int d = mtd*16 + l15;
                    int col = (kf*32 + quad*8) ^ (((d >> 3) & 7) << 3);
                    av[mtd] = *(const bf16x8*)&Vts[d][col];
                }
                #pragma unroll
                for (int nt=0;nt<2;nt++){
                    int ch = (kf*4 + quad) ^ sx;
                    bp[nt] = *(const bf16x8*)&Ps[(wave*32 + nt*16 + l15)*64 + ch*8];
                }
                #pragma unroll
                for (int mtd=0;mtd<4;mtd++)
                    #pragma unroll
                    for (int nt=0;nt<2;nt++)
                        o_acc[mtd][nt] = __builtin_amdgcn_mfma_f32_16x16x32_bf16(av[mtd], bp[nt], o_acc[mtd][nt], 0,0,0);
            }
            __syncthreads();
        }

        #pragma unroll
        for (int nt = 0; nt < 2; ++nt){
            float inv = 1.0f / l_st[nt];
            size_t tok = tb + qi*128 + wave*32 + nt*16 + l15;
            #pragma unroll
            for (int mtd = 0; mtd < 4; ++mtd){
                ushort4 ok;
                ok.x = f2bf(o_acc[mtd][nt][0]*inv); ok.y = f2bf(o_acc[mtd][nt][1]*inv);
                ok.z = f2bf(o_acc[mtd][nt][2]*inv); ok.w = f2bf(o_acc[mtd][nt][3]*inv);
                *(ushort4*)(attn_out + tok*EMB + h*64 + mtd*16 + quad*4) = ok;
            }
        }
    }
}

extern "C" void kernel_launch(void* const* d_in, const int* in_sizes, int n_in,
                              void* d_out, int out_size, void* d_ws, size_t ws_size,
                              hipStream_t stream){
    const float* x      = (const float*)d_in[0];
    const float* ln1_g  = (const float*)d_in[1];
    const float* ln1_b  = (const float*)d_in[2];
    const float* wq     = (const float*)d_in[3];
    const float* wk     = (const float*)d_in[4];
    const float* wv     = (const float*)d_in[5];
    const float* w_proj = (const float*)d_in[6];
    const float* b_proj = (const float*)d_in[7];
    const float* ln2_g  = (const float*)d_in[8];
    const float* ln2_b  = (const float*)d_in[9];
    const float* w1     = (const float*)d_in[10];
    const float* b1     = (const float*)d_in[11];
    const float* w2     = (const float*)d_in[12];
    const float* b2     = (const float*)d_in[13];
    float* outp = (float*)d_out;

    char* ws = (char*)d_ws;
    size_t off = 0;
    auto alloc = [&](size_t bytes)->char*{ char* p = ws + off; off += (bytes + 255) & ~255ULL; return p; };
    ushort_t* wqkv_t = (ushort_t*)alloc((size_t)3072*1024*2);
    ushort_t* wproj_t= (ushort_t*)alloc((size_t)1024*1024*2);
    ushort_t* w1_t   = (ushort_t*)alloc((size_t)4096*1024*2);
    ushort_t* w2_t   = (ushort_t*)alloc((size_t)1024*4096*2);
    ushort_t* qkv    = (ushort_t*)alloc((size_t)ROWS*3072*2);
    ushort_t* hbuf   = (ushort_t*)alloc((size_t)ROWS*1024*2);
    float*    out32  = (float*)  alloc((size_t)ROWS*1024*4);
    ushort_t* mid    = (ushort_t*)alloc((size_t)ROWS*4096*2);
    ushort_t* h1 = hbuf;
    ushort_t* attn = hbuf;   // h1 dead after qkv GEMM
    ushort_t* h2 = qkv;      // qkv dead after attention

    dim3 blk(256);
    dim3 gblk(512);
    // blocks: 8192 LN1 rows + 3072 (wq/wk/wv) + 1024 (wproj) + 4096 (w1) + 4096 (w2)
    prep_kernel<<<dim3(20480), blk, 0, stream>>>(x, ln1_g, ln1_b, h1,
                                                 wq, wk, wv, w_proj, w1, w2,
                                                 wqkv_t, wproj_t, w1_t, w2_t);
    // same grids as r6 (tiles unchanged), 512-thread blocks:
    gemm_kernel<0><<<dim3(64*(3072/128)), gblk, 0, stream>>>(h1, wqkv_t, nullptr, nullptr, qkv, ROWS, 3072, 1024);
    attn_kernel<<<dim3(4,128), blk, 0, stream>>>(qkv, attn);
    gemm_kernel<1><<<dim3(64*(1024/128)), gblk, 0, stream>>>(attn, wproj_t, b_proj, x, out32, ROWS, 1024, 1024);
    ln_kernel<<<ROWS, blk, 0, stream>>>(out32, ln2_g, ln2_b, h2);
    gemm_kernel<2><<<dim3(64*(4096/128)), gblk, 0, stream>>>(h2, w1_t, b1, nullptr, mid, ROWS, 4096, 1024);
    gemm_kernel<3><<<dim3(64*(1024/128)), gblk, 0, stream>>>(mid, w2_t, b2, out32, outp, ROWS, 1024, 4096);
}